// Round 4
// baseline (3038.314 us; speedup 1.0000x reference)
//
#include <hip/hip_runtime.h>
#include <hip/hip_bf16.h>

// HeteroGNN fused pipeline for MI355X.
// N=100000 nodes/type, E=1000000 edges/type, H=64, L=8.
#define NN 100000
#define NE 1000000
#define NH 6400000      // N*H elements per [N,64] buffer
#define NB 1563         // dst-buckets per message type (dst>>6; 1563*64 = 100032)
#define NBT (3 * NB)    // total bins

typedef unsigned int uint;
typedef unsigned short ushort;

// bf16 helpers (RNE)
static __device__ inline ushort f2bf(float x) {
    uint u = __float_as_uint(x);
    u = u + 0x7fffu + ((u >> 16) & 1u);
    return (ushort)(u >> 16);
}
static __device__ inline float bf2f(uint h) {   // low 16 bits hold bf16
    return __uint_as_float(h << 16);
}
static __device__ inline uint pack2(float lo, float hi) {
    return (uint)f2bf(lo) | ((uint)f2bf(hi) << 16);
}

// ---------------- zero scratch ----------------
__global__ __launch_bounds__(256) void zero_kernel(int* __restrict__ bh,
                                                   float* __restrict__ bnacc) {
    int i = blockIdx.x * 256 + threadIdx.x;
    if (i < NBT) bh[i] = 0;
    if (i < 512) bnacc[i] = 0.f;
}

// ---------------- precompute effective weights ----------------
// Weff layout: [layer][which][64][64], which: 0=Ws_eff(m0) 1=Ws_eff(m1) 2=Ws_eff(m2)
//              3=0.5*(Wd_eff(m1)+Wd_eff(m2)) 4=Wd_eff(m0)
__global__ __launch_bounds__(256) void prep_kernel(
    const float* __restrict__ Wsrc, const float* __restrict__ bsrc,
    const float* __restrict__ Wdst, const float* __restrict__ bdst,
    const float* __restrict__ Wupd, const float* __restrict__ bupd,
    float* __restrict__ Weff, float* __restrict__ by1, float* __restrict__ by0) {
    int t = blockIdx.x * 256 + threadIdx.x;
    if (t < 2 * 5 * 4096) {
        int l = t / 20480;
        int rem = t % 20480;
        int which = rem / 4096;
        int kc = rem % 4096;
        int k = kc >> 6, c = kc & 63;
        float v = 0.f;
        if (which < 3) {
            int m = which;
            const float* ws = Wsrc + (l * 3 + m) * 4096 + k * 64;
            const float* wu = Wupd + (l * 3 + m) * 8192 + 64 * 64 + c;  // bottom half rows
            for (int k2 = 0; k2 < 64; k2++) v = fmaf(ws[k2], wu[k2 * 64], v);
        } else if (which == 3) {
            const float* wd1 = Wdst + (l * 3 + 1) * 4096 + k * 64;
            const float* wu1 = Wupd + (l * 3 + 1) * 8192 + c;           // top half rows
            const float* wd2 = Wdst + (l * 3 + 2) * 4096 + k * 64;
            const float* wu2 = Wupd + (l * 3 + 2) * 8192 + c;
            for (int k2 = 0; k2 < 64; k2++)
                v += 0.5f * (wd1[k2] * wu1[k2 * 64] + wd2[k2] * wu2[k2 * 64]);
        } else {
            const float* wd = Wdst + (l * 3 + 0) * 4096 + k * 64;
            const float* wu = Wupd + (l * 3 + 0) * 8192 + c;
            for (int k2 = 0; k2 < 64; k2++) v = fmaf(wd[k2], wu[k2 * 64], v);
        }
        Weff[t] = v;
        return;
    }
    t -= 2 * 5 * 4096;
    if (t < 128) {  // by1: full b_eff of message type 0
        int l = t >> 6, c = t & 63;
        const float* wu = Wupd + (l * 3 + 0) * 8192;
        float v = bupd[(l * 3 + 0) * 64 + c];
        for (int k = 0; k < 64; k++) {
            v = fmaf(bdst[(l * 3 + 0) * 64 + k], wu[k * 64 + c], v);
            v = fmaf(bsrc[(l * 3 + 0) * 64 + k], wu[(64 + k) * 64 + c], v);
        }
        by1[l * 64 + c] = v;
        return;
    }
    t -= 128;
    if (t < 128) {  // by0 = 0.5*(b_eff(m1)+b_eff(m2))
        int l = t >> 6, c = t & 63;
        float v = 0.f;
        for (int m = 1; m <= 2; m++) {
            const float* wu = Wupd + (l * 3 + m) * 8192;
            float s = bupd[(l * 3 + m) * 64 + c];
            for (int k = 0; k < 64; k++) {
                s = fmaf(bdst[(l * 3 + m) * 64 + k], wu[k * 64 + c], s);
                s = fmaf(bsrc[(l * 3 + m) * 64 + k], wu[(64 + k) * 64 + c], s);
            }
            v += 0.5f * s;
        }
        by0[l * 64 + c] = v;
    }
}

// ---------------- bucket histogram (LDS-staged) ----------------
__global__ __launch_bounds__(256) void bhist_kernel(
    const int* __restrict__ e0, const int* __restrict__ e1,
    const int* __restrict__ e2, int* __restrict__ bh) {
    __shared__ int lh[NB];
    const int t = threadIdx.x;
    const int ty = blockIdx.y;
    const int* __restrict__ ed = ((ty == 0) ? e0 : (ty == 1) ? e1 : e2) + NE; // dst ids
    for (int i = t; i < NB; i += 256) lh[i] = 0;
    __syncthreads();
    for (int i = blockIdx.x * 256 + t; i < NE; i += 128 * 256)
        atomicAdd(&lh[ed[i] >> 6], 1);
    __syncthreads();
    for (int i = t; i < NB; i += 256) {
        int v = lh[i];
        if (v) atomicAdd(&bh[ty * NB + i], v);
    }
}

// ---------------- bucket scan (one block over 4689 bins) ----------------
__global__ __launch_bounds__(256) void bscan_kernel(const int* __restrict__ bh,
                                                    int* __restrict__ boffs,
                                                    int* __restrict__ bcur) {
    __shared__ int s[256];
    __shared__ int carry;
    const int t = threadIdx.x;
    if (t == 0) carry = 0;
    __syncthreads();
    for (int base = 0; base < NBT; base += 256) {
        int i = base + t;
        int v = (i < NBT) ? bh[i] : 0;
        s[t] = v;
        __syncthreads();
        for (int d = 1; d < 256; d <<= 1) {
            int tv = (t >= d) ? s[t - d] : 0;
            __syncthreads();
            s[t] += tv;
            __syncthreads();
        }
        if (i < NBT) {
            int ex = s[t] - v + carry;
            boffs[i] = ex;
            bcur[i] = ex;
        }
        __syncthreads();
        if (t == 0) carry += s[255];
        __syncthreads();
    }
    if (t == 0) boffs[NBT] = carry;   // = 3E
}

// ---------------- bucket scatter (packed (dst&63)<<17 | src) ----------------
__global__ __launch_bounds__(256) void bscat_kernel(
    const int* __restrict__ e0, const int* __restrict__ e1,
    const int* __restrict__ e2, int* __restrict__ bcur, uint* __restrict__ be) {
    int i = blockIdx.x * 256 + threadIdx.x;
    if (i >= NE) return;
    int ty = blockIdx.y;
    const int* e = (ty == 0) ? e0 : (ty == 1) ? e1 : e2;
    int s = e[i], d = e[NE + i];
    int pos = atomicAdd(&bcur[ty * NB + (d >> 6)], 1);
    be[pos] = ((uint)(d & 63) << 17) | (uint)s;
}

// ---------------- fused multi-output GEMM ----------------
// grid (782, 2). ty=0: A = x0-type, outputs {0,2,3}; ty=1: A = x1-type, {1,4}.
// A-tile staged once in LDS [128][65]; outputs stored bf16 (full-line stores).
template <bool BN>
__global__ __launch_bounds__(256) void gemmA_kernel(
    const float* __restrict__ x0, const float* __restrict__ x1,
    const float* __restrict__ Weff, const float* __restrict__ ss0,
    const float* __restrict__ ss1, uint* __restrict__ Tb) {
    __shared__ float la[128 * 65];
    const int ty = blockIdx.y;
    const float* __restrict__ A = ty ? x1 : x0;
    const float* __restrict__ ss = ty ? ss1 : ss0;
    const int t = threadIdx.x;
    const int base = blockIdx.x * 128;
#pragma unroll
    for (int i = 0; i < 8; i++) {
        int chunk = i * 256 + t;
        int r = chunk >> 4, c4 = chunk & 15;
        int grow = base + r;
        float4 v = make_float4(0.f, 0.f, 0.f, 0.f);
        if (grow < NN)
            v = *reinterpret_cast<const float4*>(A + (size_t)grow * 64 + c4 * 4);
        if (BN) {
            float4 sc = *reinterpret_cast<const float4*>(ss + c4 * 4);
            float4 sh = *reinterpret_cast<const float4*>(ss + 64 + c4 * 4);
            v.x = fmaf(v.x, sc.x, sh.x); v.x = v.x >= 0.f ? v.x : 0.01f * v.x;
            v.y = fmaf(v.y, sc.y, sh.y); v.y = v.y >= 0.f ? v.y : 0.01f * v.y;
            v.z = fmaf(v.z, sc.z, sh.z); v.z = v.z >= 0.f ? v.z : 0.01f * v.z;
            v.w = fmaf(v.w, sc.w, sh.w); v.w = v.w >= 0.f ? v.w : 0.01f * v.w;
        }
        int lb = r * 65 + c4 * 4;
        la[lb] = v.x; la[lb + 1] = v.y; la[lb + 2] = v.z; la[lb + 3] = v.w;
    }
    __syncthreads();
    const int cg = t & 7, rr = t >> 3;
    const int rb = rr * 4 * 65;
    const int nout = ty ? 2 : 3;
#pragma unroll
    for (int o = 0; o < 3; o++) {
        if (o >= nout) break;
        const int which = ty ? (o == 0 ? 1 : 4) : (o == 0 ? 0 : (o == 1 ? 2 : 3));
        const float* __restrict__ W = Weff + which * 4096;
        float4 a0c[4], a1c[4];
#pragma unroll
        for (int j = 0; j < 4; j++) {
            a0c[j] = make_float4(0.f, 0.f, 0.f, 0.f);
            a1c[j] = make_float4(0.f, 0.f, 0.f, 0.f);
        }
#pragma unroll 8
        for (int k = 0; k < 64; k++) {
            float a0 = la[rb + k];
            float a1 = la[rb + 65 + k];
            float a2 = la[rb + 130 + k];
            float a3 = la[rb + 195 + k];
            const float4* w4 = reinterpret_cast<const float4*>(W + k * 64 + cg * 8);
            float4 w0 = w4[0], w1 = w4[1];
            a0c[0].x = fmaf(a0, w0.x, a0c[0].x); a0c[0].y = fmaf(a0, w0.y, a0c[0].y);
            a0c[0].z = fmaf(a0, w0.z, a0c[0].z); a0c[0].w = fmaf(a0, w0.w, a0c[0].w);
            a1c[0].x = fmaf(a0, w1.x, a1c[0].x); a1c[0].y = fmaf(a0, w1.y, a1c[0].y);
            a1c[0].z = fmaf(a0, w1.z, a1c[0].z); a1c[0].w = fmaf(a0, w1.w, a1c[0].w);
            a0c[1].x = fmaf(a1, w0.x, a0c[1].x); a0c[1].y = fmaf(a1, w0.y, a0c[1].y);
            a0c[1].z = fmaf(a1, w0.z, a0c[1].z); a0c[1].w = fmaf(a1, w0.w, a0c[1].w);
            a1c[1].x = fmaf(a1, w1.x, a1c[1].x); a1c[1].y = fmaf(a1, w1.y, a1c[1].y);
            a1c[1].z = fmaf(a1, w1.z, a1c[1].z); a1c[1].w = fmaf(a1, w1.w, a1c[1].w);
            a0c[2].x = fmaf(a2, w0.x, a0c[2].x); a0c[2].y = fmaf(a2, w0.y, a0c[2].y);
            a0c[2].z = fmaf(a2, w0.z, a0c[2].z); a0c[2].w = fmaf(a2, w0.w, a0c[2].w);
            a1c[2].x = fmaf(a2, w1.x, a1c[2].x); a1c[2].y = fmaf(a2, w1.y, a1c[2].y);
            a1c[2].z = fmaf(a2, w1.z, a1c[2].z); a1c[2].w = fmaf(a2, w1.w, a1c[2].w);
            a0c[3].x = fmaf(a3, w0.x, a0c[3].x); a0c[3].y = fmaf(a3, w0.y, a0c[3].y);
            a0c[3].z = fmaf(a3, w0.z, a0c[3].z); a0c[3].w = fmaf(a3, w0.w, a0c[3].w);
            a1c[3].x = fmaf(a3, w1.x, a1c[3].x); a1c[3].y = fmaf(a3, w1.y, a1c[3].y);
            a1c[3].z = fmaf(a3, w1.z, a1c[3].z); a1c[3].w = fmaf(a3, w1.w, a1c[3].w);
        }
        uint* __restrict__ out = Tb + (size_t)which * (NH / 2);
#pragma unroll
        for (int j = 0; j < 4; j++) {
            int grow = base + rr * 4 + j;
            if (grow < NN) {
                uint4 pk;
                pk.x = pack2(a0c[j].x, a0c[j].y);
                pk.y = pack2(a0c[j].z, a0c[j].w);
                pk.z = pack2(a1c[j].x, a1c[j].y);
                pk.w = pack2(a1c[j].z, a1c[j].w);
                *reinterpret_cast<uint4*>(out + (size_t)grow * 32 + cg * 4) = pk;
            }
        }
    }
}

// ---------------- bucketed aggregation: y1 (message type 0) ----------------
// Block = one bucket of 64 dst rows. LDS fp32 accumulate + count, then
// finalize y1 = D1 + mean + bias, with BN stats fused (column partials).
__global__ __launch_bounds__(256) void aggB1_kernel(
    const uint* __restrict__ T0, const uint* __restrict__ D1,
    const int* __restrict__ boffs, const uint* __restrict__ be,
    const float* __restrict__ by, float* __restrict__ y1,
    float* __restrict__ bnacc) {
    __shared__ float acc[64 * 64];
    __shared__ int lcnt[64];
    __shared__ float rs[4][64], rq[4][64];
    const int t = threadIdx.x;
    const int b = blockIdx.x;
    for (int i = t; i < 4096; i += 256) acc[i] = 0.f;
    if (t < 64) lcnt[t] = 0;
    __syncthreads();
    const int o0 = boffs[b], o1 = boffs[b + 1];
    const int wv = t >> 6, hl = (t >> 5) & 1, c = t & 31;
    for (int j = o0 + wv * 2 + hl; j < o1; j += 8) {
        uint pk = be[j];
        int src = pk & 0x1ffff;
        int dl = pk >> 17;
        uint u = T0[(size_t)src * 32 + c];
        atomicAdd(&acc[dl * 64 + 2 * c], bf2f(u & 0xffffu));
        atomicAdd(&acc[dl * 64 + 2 * c + 1], bf2f(u >> 16));
        if (c == 0) atomicAdd(&lcnt[dl], 1);
    }
    __syncthreads();
    const int col = t & 63, rg = t >> 6;
    float s = 0.f, q = 0.f;
    for (int r = rg * 16; r < rg * 16 + 16; r++) {
        int grow = b * 64 + r;
        if (grow >= NN) break;
        int d = lcnt[r];
        float inv = 1.f / (float)(d > 1 ? d : 1);
        uint dd = D1[(size_t)grow * 32 + (col >> 1)];
        float dv = bf2f((col & 1) ? (dd >> 16) : (dd & 0xffffu));
        float val = dv + acc[r * 64 + col] * inv + by[col];
        y1[(size_t)grow * 64 + col] = val;
        s += val;
        q = fmaf(val, val, q);
    }
    rs[rg][col] = s;
    rq[rg][col] = q;
    __syncthreads();
    if (rg == 0) {
        s = rs[0][col] + rs[1][col] + rs[2][col] + rs[3][col];
        q = rq[0][col] + rq[1][col] + rq[2][col] + rq[3][col];
        atomicAdd(&bnacc[col], s);
        atomicAdd(&bnacc[64 + col], q);
    }
}

// ---------------- bucketed aggregation: y0 (message types 1 & 2) ----------------
__global__ __launch_bounds__(256) void aggB0_kernel(
    const uint* __restrict__ T1, const uint* __restrict__ T2,
    const uint* __restrict__ D0, const int* __restrict__ boffs,
    const uint* __restrict__ be, const float* __restrict__ by,
    float* __restrict__ y0, float* __restrict__ bnacc) {
    __shared__ float acc1[64 * 64];
    __shared__ float acc2[64 * 64];
    __shared__ int lcnt1[64], lcnt2[64];
    __shared__ float rs[4][64], rq[4][64];
    const int t = threadIdx.x;
    const int b = blockIdx.x;
    for (int i = t; i < 4096; i += 256) { acc1[i] = 0.f; acc2[i] = 0.f; }
    if (t < 64) { lcnt1[t] = 0; lcnt2[t] = 0; }
    __syncthreads();
    const int wv = t >> 6, hl = (t >> 5) & 1, c = t & 31;
    {
        const int o0 = boffs[NB + b], o1 = boffs[NB + b + 1];
        for (int j = o0 + wv * 2 + hl; j < o1; j += 8) {
            uint pk = be[j];
            int src = pk & 0x1ffff;
            int dl = pk >> 17;
            uint u = T1[(size_t)src * 32 + c];
            atomicAdd(&acc1[dl * 64 + 2 * c], bf2f(u & 0xffffu));
            atomicAdd(&acc1[dl * 64 + 2 * c + 1], bf2f(u >> 16));
            if (c == 0) atomicAdd(&lcnt1[dl], 1);
        }
    }
    {
        const int o0 = boffs[2 * NB + b], o1 = boffs[2 * NB + b + 1];
        for (int j = o0 + wv * 2 + hl; j < o1; j += 8) {
            uint pk = be[j];
            int src = pk & 0x1ffff;
            int dl = pk >> 17;
            uint u = T2[(size_t)src * 32 + c];
            atomicAdd(&acc2[dl * 64 + 2 * c], bf2f(u & 0xffffu));
            atomicAdd(&acc2[dl * 64 + 2 * c + 1], bf2f(u >> 16));
            if (c == 0) atomicAdd(&lcnt2[dl], 1);
        }
    }
    __syncthreads();
    const int col = t & 63, rg = t >> 6;
    float s = 0.f, q = 0.f;
    for (int r = rg * 16; r < rg * 16 + 16; r++) {
        int grow = b * 64 + r;
        if (grow >= NN) break;
        int d1 = lcnt1[r], d2 = lcnt2[r];
        float i1 = 1.f / (float)(d1 > 1 ? d1 : 1);
        float i2 = 1.f / (float)(d2 > 1 ? d2 : 1);
        uint dd = D0[(size_t)grow * 32 + (col >> 1)];
        float dv = bf2f((col & 1) ? (dd >> 16) : (dd & 0xffffu));
        float val = dv + 0.5f * (acc1[r * 64 + col] * i1 + acc2[r * 64 + col] * i2)
                    + by[col];
        y0[(size_t)grow * 64 + col] = val;
        s += val;
        q = fmaf(val, val, q);
    }
    rs[rg][col] = s;
    rq[rg][col] = q;
    __syncthreads();
    if (rg == 0) {
        s = rs[0][col] + rs[1][col] + rs[2][col] + rs[3][col];
        q = rq[0][col] + rq[1][col] + rq[2][col] + rq[3][col];
        atomicAdd(&bnacc[col], s);
        atomicAdd(&bnacc[64 + col], q);
    }
}

// ---------------- batch-norm finalize ----------------
__global__ void bn_fin_kernel(const float* __restrict__ acc,
                              const float* __restrict__ gamma,
                              const float* __restrict__ beta,
                              float* __restrict__ bnss, int l) {
    int t = threadIdx.x;
    if (t >= 128) return;
    int ty = t >> 6, c = t & 63;
    int idx = l * 2 + ty;
    const float invn = 1.0f / (float)NN;
    float mean = acc[idx * 128 + c] * invn;
    float msq = acc[idx * 128 + 64 + c] * invn;
    float var = msq - mean * mean;
    float rs = 1.0f / sqrtf(var + 1.0f);   // eps = 1.0 per reference
    float scv = rs * gamma[idx * 64 + c];
    bnss[idx * 128 + c] = scv;
    bnss[idx * 128 + 64 + c] = beta[idx * 64 + c] - mean * scv;
}

// ---------------- head: out = leaky(bn(y)) @ Wp + bp ----------------
__global__ __launch_bounds__(256) void head_kernel(
    const float* __restrict__ y0, const float* __restrict__ y1,
    const float* __restrict__ Wp, const float* __restrict__ bp,
    const float* __restrict__ ssb, float* __restrict__ outb) {
    constexpr int KPH = 68;
    __shared__ float lw[512];
    __shared__ float la[64 * KPH];
    const int ty = blockIdx.y;
    const float* __restrict__ A = ty ? y1 : y0;
    const float* __restrict__ ss = ssb + ty * 128;
    float* __restrict__ out = outb + (size_t)ty * (NN * 8);
    const int t = threadIdx.x;
    for (int i = t; i < 512; i += 256) lw[i] = Wp[ty * 512 + i];
    const int col = t & 63, rg = t >> 6;
    const float sc = ss[col], sh = ss[64 + col];
    const int base = blockIdx.x * 64;
    const int swz = (col & 3) << 3;
#pragma unroll
    for (int i = 0; i < 16; i++) {
        int r = rg * 16 + i;
        int grow = base + r;
        float v = 0.f;
        if (grow < NN) {
            v = A[(size_t)grow * 64 + col];
            v = fmaf(v, sc, sh);
            v = (v >= 0.f) ? v : 0.01f * v;
        }
        la[col * KPH + (r ^ swz)] = v;
    }
    __syncthreads();
    const int c = t & 7, rp = t >> 3;
    float o0 = 0.f, o1 = 0.f;
#pragma unroll
    for (int k = 0; k < 64; k++) {
        float w = lw[k * 8 + c];
        int pos = k * KPH + ((rp * 2) ^ ((k & 3) << 3));
        o0 = fmaf(la[pos], w, o0);
        o1 = fmaf(la[pos + 1], w, o1);
    }
    float b = bp[ty * 8 + c];
    int g0 = base + rp * 2;
    if (g0 < NN) out[(size_t)g0 * 8 + c] = o0 + b;
    if (g0 + 1 < NN) out[(size_t)(g0 + 1) * 8 + c] = o1 + b;
}

// ---------------- launch ----------------
extern "C" void kernel_launch(void* const* d_in, const int* in_sizes, int n_in,
                              void* d_out, int out_size, void* d_ws, size_t ws_size,
                              hipStream_t stream) {
    const float* x0 = (const float*)d_in[0];
    const float* x1 = (const float*)d_in[1];
    const int* e0 = (const int*)d_in[2];
    const int* e1 = (const int*)d_in[3];
    const int* e2 = (const int*)d_in[4];
    const float* Wsrc = (const float*)d_in[5];
    const float* bsrc = (const float*)d_in[6];
    const float* Wdst = (const float*)d_in[7];
    const float* bdst = (const float*)d_in[8];
    const float* Wupd = (const float*)d_in[9];
    const float* bupd = (const float*)d_in[10];
    const float* gamma = (const float*)d_in[11];
    const float* beta = (const float*)d_in[12];
    const float* Wp = (const float*)d_in[13];
    const float* bp = (const float*)d_in[14];
    float* outp = (float*)d_out;

    // workspace layout (~128 MB)
    uint* Tb = (uint*)d_ws;               // 5 bf16 buffers [N,64]: 5*NH/2 uints
    float* y0 = (float*)(Tb + 5 * (NH / 2));
    float* y1 = y0 + NH;
    float* Weff = y1 + NH;                // 2*5*4096 = 40960
    float* by1p = Weff + 40960;           // 128
    float* by0p = by1p + 128;             // 128
    float* bnacc = by0p + 128;            // 512
    float* bnss = bnacc + 512;            // 512
    int* bh = (int*)(bnss + 512);         // NBT
    int* boffs = bh + NBT;                // NBT + 1
    int* bcur = boffs + NBT + 1;          // NBT
    uint* be = (uint*)(bcur + NBT);       // 3E packed bucketed edges
    (void)in_sizes; (void)n_in; (void)out_size; (void)ws_size;

    const uint* T0 = Tb;
    const uint* T1 = Tb + 1 * (NH / 2);
    const uint* T2 = Tb + 2 * (NH / 2);
    const uint* D0 = Tb + 3 * (NH / 2);
    const uint* D1 = Tb + 4 * (NH / 2);

    // ---- bucket build + weight prep ----
    zero_kernel<<<19, 256, 0, stream>>>(bh, bnacc);
    prep_kernel<<<161, 256, 0, stream>>>(Wsrc, bsrc, Wdst, bdst, Wupd, bupd,
                                         Weff, by1p, by0p);
    bhist_kernel<<<dim3(128, 3), 256, 0, stream>>>(e0, e1, e2, bh);
    bscan_kernel<<<1, 256, 0, stream>>>(bh, boffs, bcur);
    bscat_kernel<<<dim3(3907, 3), 256, 0, stream>>>(e0, e1, e2, bcur, be);

    // ---- layer 0 ----
    gemmA_kernel<false><<<dim3(782, 2), 256, 0, stream>>>(x0, x1, Weff, nullptr,
                                                          nullptr, Tb);
    aggB1_kernel<<<NB, 256, 0, stream>>>(T0, D1, boffs, be, by1p, y1,
                                         bnacc + 128);
    aggB0_kernel<<<NB, 256, 0, stream>>>(T1, T2, D0, boffs, be, by0p, y0,
                                         bnacc);
    bn_fin_kernel<<<1, 128, 0, stream>>>(bnacc, gamma, beta, bnss, 0);

    // ---- layer 1 (BN+leaky fused into GEMM loads) ----
    gemmA_kernel<true><<<dim3(782, 2), 256, 0, stream>>>(y0, y1, Weff + 20480,
                                                         bnss, bnss + 128, Tb);
    aggB1_kernel<<<NB, 256, 0, stream>>>(T0, D1, boffs, be, by1p + 64, y1,
                                         bnacc + 256 + 128);
    aggB0_kernel<<<NB, 256, 0, stream>>>(T1, T2, D0, boffs, be, by0p + 64, y0,
                                         bnacc + 256);
    bn_fin_kernel<<<1, 128, 0, stream>>>(bnacc, gamma, beta, bnss, 1);

    // ---- heads (BN+leaky fused) ----
    head_kernel<<<dim3(1563, 2), 256, 0, stream>>>(y0, y1, Wp, bp, bnss + 256, outp);
}

// Round 6
// 1226.704 us; speedup vs baseline: 2.4768x; 2.4768x over previous
//
#include <hip/hip_runtime.h>
#include <hip/hip_bf16.h>

// HeteroGNN fused pipeline for MI355X.
// N=100000 nodes/type, E=1000000 edges/type, H=64, L=8.
#define NN 100000
#define NE 1000000
#define NH 6400000      // N*H elements per [N,64] buffer
#define NB 1563         // dst-buckets per message type (dst>>6; 1563*64 = 100032)
#define NBT (3 * NB)    // total buckets
#define NR 100032       // padded rows per type (rowoffs stride)

typedef unsigned int uint;
typedef unsigned short ushort;

// bf16 helpers (RNE)
static __device__ inline ushort f2bf(float x) {
    uint u = __float_as_uint(x);
    u = u + 0x7fffu + ((u >> 16) & 1u);
    return (ushort)(u >> 16);
}
static __device__ inline float bf2f(uint h) {   // low 16 bits hold bf16
    return __uint_as_float(h << 16);
}
static __device__ inline uint pack2(float lo, float hi) {
    return (uint)f2bf(lo) | ((uint)f2bf(hi) << 16);
}

// ---------------- zero scratch ----------------
__global__ __launch_bounds__(256) void zero_kernel(int* __restrict__ bh,
                                                   float* __restrict__ bnacc) {
    int i = blockIdx.x * 256 + threadIdx.x;
    if (i < NBT) bh[i] = 0;
    if (i < 512) bnacc[i] = 0.f;
}

// ---------------- precompute effective weights ----------------
// Weff layout: [layer][which][64][64], which: 0=Ws_eff(m0) 1=Ws_eff(m1) 2=Ws_eff(m2)
//              3=0.5*(Wd_eff(m1)+Wd_eff(m2)) 4=Wd_eff(m0)
__global__ __launch_bounds__(256) void prep_kernel(
    const float* __restrict__ Wsrc, const float* __restrict__ bsrc,
    const float* __restrict__ Wdst, const float* __restrict__ bdst,
    const float* __restrict__ Wupd, const float* __restrict__ bupd,
    float* __restrict__ Weff, float* __restrict__ by1, float* __restrict__ by0) {
    int t = blockIdx.x * 256 + threadIdx.x;
    if (t < 2 * 5 * 4096) {
        int l = t / 20480;
        int rem = t % 20480;
        int which = rem / 4096;
        int kc = rem % 4096;
        int k = kc >> 6, c = kc & 63;
        float v = 0.f;
        if (which < 3) {
            int m = which;
            const float* ws = Wsrc + (l * 3 + m) * 4096 + k * 64;
            const float* wu = Wupd + (l * 3 + m) * 8192 + 64 * 64 + c;  // bottom half rows
            for (int k2 = 0; k2 < 64; k2++) v = fmaf(ws[k2], wu[k2 * 64], v);
        } else if (which == 3) {
            const float* wd1 = Wdst + (l * 3 + 1) * 4096 + k * 64;
            const float* wu1 = Wupd + (l * 3 + 1) * 8192 + c;           // top half rows
            const float* wd2 = Wdst + (l * 3 + 2) * 4096 + k * 64;
            const float* wu2 = Wupd + (l * 3 + 2) * 8192 + c;
            for (int k2 = 0; k2 < 64; k2++)
                v += 0.5f * (wd1[k2] * wu1[k2 * 64] + wd2[k2] * wu2[k2 * 64]);
        } else {
            const float* wd = Wdst + (l * 3 + 0) * 4096 + k * 64;
            const float* wu = Wupd + (l * 3 + 0) * 8192 + c;
            for (int k2 = 0; k2 < 64; k2++) v = fmaf(wd[k2], wu[k2 * 64], v);
        }
        Weff[t] = v;
        return;
    }
    t -= 2 * 5 * 4096;
    if (t < 128) {  // by1: full b_eff of message type 0
        int l = t >> 6, c = t & 63;
        const float* wu = Wupd + (l * 3 + 0) * 8192;
        float v = bupd[(l * 3 + 0) * 64 + c];
        for (int k = 0; k < 64; k++) {
            v = fmaf(bdst[(l * 3 + 0) * 64 + k], wu[k * 64 + c], v);
            v = fmaf(bsrc[(l * 3 + 0) * 64 + k], wu[(64 + k) * 64 + c], v);
        }
        by1[l * 64 + c] = v;
        return;
    }
    t -= 128;
    if (t < 128) {  // by0 = 0.5*(b_eff(m1)+b_eff(m2))
        int l = t >> 6, c = t & 63;
        float v = 0.f;
        for (int m = 1; m <= 2; m++) {
            const float* wu = Wupd + (l * 3 + m) * 8192;
            float s = bupd[(l * 3 + m) * 64 + c];
            for (int k = 0; k < 64; k++) {
                s = fmaf(bdst[(l * 3 + m) * 64 + k], wu[k * 64 + c], s);
                s = fmaf(bsrc[(l * 3 + m) * 64 + k], wu[(64 + k) * 64 + c], s);
            }
            v += 0.5f * s;
        }
        by0[l * 64 + c] = v;
    }
}

// ---------------- bucket histogram (LDS-staged) ----------------
__global__ __launch_bounds__(256) void bhist_kernel(
    const int* __restrict__ e0, const int* __restrict__ e1,
    const int* __restrict__ e2, int* __restrict__ bh) {
    __shared__ int lh[NB];
    const int t = threadIdx.x;
    const int ty = blockIdx.y;
    const int* __restrict__ ed = ((ty == 0) ? e0 : (ty == 1) ? e1 : e2) + NE; // dst ids
    for (int i = t; i < NB; i += 256) lh[i] = 0;
    __syncthreads();
    for (int i = blockIdx.x * 256 + t; i < NE; i += 128 * 256)
        atomicAdd(&lh[ed[i] >> 6], 1);
    __syncthreads();
    for (int i = t; i < NB; i += 256) {
        int v = lh[i];
        if (v) atomicAdd(&bh[ty * NB + i], v);
    }
}

// ---------------- bucket scan (one block over 4689 bins) ----------------
__global__ __launch_bounds__(256) void bscan_kernel(const int* __restrict__ bh,
                                                    int* __restrict__ boffs,
                                                    int* __restrict__ bcur) {
    __shared__ int s[256];
    __shared__ int carry;
    const int t = threadIdx.x;
    if (t == 0) carry = 0;
    __syncthreads();
    for (int base = 0; base < NBT; base += 256) {
        int i = base + t;
        int v = (i < NBT) ? bh[i] : 0;
        s[t] = v;
        __syncthreads();
        for (int d = 1; d < 256; d <<= 1) {
            int tv = (t >= d) ? s[t - d] : 0;
            __syncthreads();
            s[t] += tv;
            __syncthreads();
        }
        if (i < NBT) {
            int ex = s[t] - v + carry;
            boffs[i] = ex;
            bcur[i] = ex;
        }
        __syncthreads();
        if (t == 0) carry += s[255];
        __syncthreads();
    }
    if (t == 0) boffs[NBT] = 3 * NE;
}

// ---------------- bucket scatter (packed (dst&63)<<17 | src) ----------------
__global__ __launch_bounds__(256) void bscat_kernel(
    const int* __restrict__ e0, const int* __restrict__ e1,
    const int* __restrict__ e2, int* __restrict__ bcur, uint* __restrict__ be) {
    int i = blockIdx.x * 256 + threadIdx.x;
    if (i >= NE) return;
    int ty = blockIdx.y;
    const int* e = (ty == 0) ? e0 : (ty == 1) ? e1 : e2;
    int s = e[i], d = e[NE + i];
    int pos = atomicAdd(&bcur[ty * NB + (d >> 6)], 1);
    be[pos] = ((uint)(d & 63) << 17) | (uint)s;
}

// ---------------- per-bucket counting sort -> dst-sorted CSR + row offsets ----
// Block = one bucket (64 dst rows). Two streaming passes over the bucket
// segment of `be`; LDS 64-bin count + serial prefix; scatter src ids into the
// bucket's contiguous csr window; emit per-row start offsets (rowoffs).
__global__ __launch_bounds__(256) void bsort_kernel(
    const int* __restrict__ boffs, const uint* __restrict__ be,
    int* __restrict__ csr, int* __restrict__ rowoffs) {
    __shared__ int cnt[64];
    __shared__ int pre[64];
    __shared__ int cur[64];
    const int t = threadIdx.x;
    const int ty = blockIdx.y;
    const int g = ty * NB + blockIdx.x;
    const int o0 = boffs[g], o1 = boffs[g + 1];
    if (t < 64) cnt[t] = 0;
    __syncthreads();
    for (int j = o0 + t; j < o1; j += 256) atomicAdd(&cnt[be[j] >> 17], 1);
    __syncthreads();
    if (t == 0) {
        int run = o0;
        for (int i = 0; i < 64; i++) { pre[i] = run; run += cnt[i]; }
    }
    __syncthreads();
    if (t < 64) {
        cur[t] = pre[t];
        rowoffs[ty * NR + blockIdx.x * 64 + t] = pre[t];
    }
    __syncthreads();
    for (int j = o0 + t; j < o1; j += 256) {
        uint pk = be[j];
        int pos = atomicAdd(&cur[pk >> 17], 1);
        csr[pos] = (int)(pk & 0x1ffffu);
    }
}

// ---------------- fused multi-output GEMM ----------------
// grid (782, 2). ty=0: A = x0-type, outputs {0,2,3}; ty=1: A = x1-type, {1,4}.
// A-tile staged once in LDS [128][65]; outputs stored bf16 (full-line stores).
template <bool BN>
__global__ __launch_bounds__(256) void gemmA_kernel(
    const float* __restrict__ x0, const float* __restrict__ x1,
    const float* __restrict__ Weff, const float* __restrict__ ss0,
    const float* __restrict__ ss1, uint* __restrict__ Tb) {
    __shared__ float la[128 * 65];
    const int ty = blockIdx.y;
    const float* __restrict__ A = ty ? x1 : x0;
    const float* __restrict__ ss = ty ? ss1 : ss0;
    const int t = threadIdx.x;
    const int base = blockIdx.x * 128;
#pragma unroll
    for (int i = 0; i < 8; i++) {
        int chunk = i * 256 + t;
        int r = chunk >> 4, c4 = chunk & 15;
        int grow = base + r;
        float4 v = make_float4(0.f, 0.f, 0.f, 0.f);
        if (grow < NN)
            v = *reinterpret_cast<const float4*>(A + (size_t)grow * 64 + c4 * 4);
        if (BN) {
            float4 sc = *reinterpret_cast<const float4*>(ss + c4 * 4);
            float4 sh = *reinterpret_cast<const float4*>(ss + 64 + c4 * 4);
            v.x = fmaf(v.x, sc.x, sh.x); v.x = v.x >= 0.f ? v.x : 0.01f * v.x;
            v.y = fmaf(v.y, sc.y, sh.y); v.y = v.y >= 0.f ? v.y : 0.01f * v.y;
            v.z = fmaf(v.z, sc.z, sh.z); v.z = v.z >= 0.f ? v.z : 0.01f * v.z;
            v.w = fmaf(v.w, sc.w, sh.w); v.w = v.w >= 0.f ? v.w : 0.01f * v.w;
        }
        int lb = r * 65 + c4 * 4;
        la[lb] = v.x; la[lb + 1] = v.y; la[lb + 2] = v.z; la[lb + 3] = v.w;
    }
    __syncthreads();
    const int cg = t & 7, rr = t >> 3;
    const int rb = rr * 4 * 65;
    const int nout = ty ? 2 : 3;
#pragma unroll
    for (int o = 0; o < 3; o++) {
        if (o >= nout) break;
        const int which = ty ? (o == 0 ? 1 : 4) : (o == 0 ? 0 : (o == 1 ? 2 : 3));
        const float* __restrict__ W = Weff + which * 4096;
        float4 a0c[4], a1c[4];
#pragma unroll
        for (int j = 0; j < 4; j++) {
            a0c[j] = make_float4(0.f, 0.f, 0.f, 0.f);
            a1c[j] = make_float4(0.f, 0.f, 0.f, 0.f);
        }
#pragma unroll 8
        for (int k = 0; k < 64; k++) {
            float a0 = la[rb + k];
            float a1 = la[rb + 65 + k];
            float a2 = la[rb + 130 + k];
            float a3 = la[rb + 195 + k];
            const float4* w4 = reinterpret_cast<const float4*>(W + k * 64 + cg * 8);
            float4 w0 = w4[0], w1 = w4[1];
            a0c[0].x = fmaf(a0, w0.x, a0c[0].x); a0c[0].y = fmaf(a0, w0.y, a0c[0].y);
            a0c[0].z = fmaf(a0, w0.z, a0c[0].z); a0c[0].w = fmaf(a0, w0.w, a0c[0].w);
            a1c[0].x = fmaf(a0, w1.x, a1c[0].x); a1c[0].y = fmaf(a0, w1.y, a1c[0].y);
            a1c[0].z = fmaf(a0, w1.z, a1c[0].z); a1c[0].w = fmaf(a0, w1.w, a1c[0].w);
            a0c[1].x = fmaf(a1, w0.x, a0c[1].x); a0c[1].y = fmaf(a1, w0.y, a0c[1].y);
            a0c[1].z = fmaf(a1, w0.z, a0c[1].z); a0c[1].w = fmaf(a1, w0.w, a0c[1].w);
            a1c[1].x = fmaf(a1, w1.x, a1c[1].x); a1c[1].y = fmaf(a1, w1.y, a1c[1].y);
            a1c[1].z = fmaf(a1, w1.z, a1c[1].z); a1c[1].w = fmaf(a1, w1.w, a1c[1].w);
            a0c[2].x = fmaf(a2, w0.x, a0c[2].x); a0c[2].y = fmaf(a2, w0.y, a0c[2].y);
            a0c[2].z = fmaf(a2, w0.z, a0c[2].z); a0c[2].w = fmaf(a2, w0.w, a0c[2].w);
            a1c[2].x = fmaf(a2, w1.x, a1c[2].x); a1c[2].y = fmaf(a2, w1.y, a1c[2].y);
            a1c[2].z = fmaf(a2, w1.z, a1c[2].z); a1c[2].w = fmaf(a2, w1.w, a1c[2].w);
            a0c[3].x = fmaf(a3, w0.x, a0c[3].x); a0c[3].y = fmaf(a3, w0.y, a0c[3].y);
            a0c[3].z = fmaf(a3, w0.z, a0c[3].z); a0c[3].w = fmaf(a3, w0.w, a0c[3].w);
            a1c[3].x = fmaf(a3, w1.x, a1c[3].x); a1c[3].y = fmaf(a3, w1.y, a1c[3].y);
            a1c[3].z = fmaf(a3, w1.z, a1c[3].z); a1c[3].w = fmaf(a3, w1.w, a1c[3].w);
        }
        uint* __restrict__ out = Tb + (size_t)which * (NH / 2);
#pragma unroll
        for (int j = 0; j < 4; j++) {
            int grow = base + rr * 4 + j;
            if (grow < NN) {
                uint4 pk;
                pk.x = pack2(a0c[j].x, a0c[j].y);
                pk.y = pack2(a0c[j].z, a0c[j].w);
                pk.z = pack2(a1c[j].x, a1c[j].y);
                pk.w = pack2(a1c[j].z, a1c[j].w);
                *reinterpret_cast<uint4*>(out + (size_t)grow * 32 + cg * 4) = pk;
            }
        }
    }
}

// ---------------- aggregation (CSR mean-gather, bf16 T/D, fp32 y out) ----------------
// thread = (row, lane) with 32 lanes covering 64 cols as bf16 pairs.
__global__ __launch_bounds__(256) void agg_y1_kernel(
    const uint* __restrict__ T0, const uint* __restrict__ D1,
    const int* __restrict__ rowoffs, const int* __restrict__ csr,
    const float* __restrict__ by, float* __restrict__ y1) {
    int gid = blockIdx.x * 256 + threadIdx.x;
    int row = gid >> 5, lane = gid & 31;
    if (row >= NN) return;
    int o0 = rowoffs[row], o1 = rowoffs[row + 1];
    float s0 = 0.f, s1 = 0.f;
    for (int j = o0; j < o1; j++) {
        uint u = T0[(size_t)csr[j] * 32 + lane];
        s0 += bf2f(u & 0xffffu);
        s1 += bf2f(u >> 16);
    }
    int d = o1 - o0;
    float inv = 1.f / (float)(d > 1 ? d : 1);
    uint dd = D1[(size_t)row * 32 + lane];
    float* yr = y1 + (size_t)row * 64 + lane * 2;
    yr[0] = bf2f(dd & 0xffffu) + s0 * inv + by[lane * 2];
    yr[1] = bf2f(dd >> 16) + s1 * inv + by[lane * 2 + 1];
}

__global__ __launch_bounds__(256) void agg_y0_kernel(
    const uint* __restrict__ T1, const uint* __restrict__ T2,
    const uint* __restrict__ D0, const int* __restrict__ rowoffs,
    const int* __restrict__ csr, const float* __restrict__ by,
    float* __restrict__ y0) {
    int gid = blockIdx.x * 256 + threadIdx.x;
    int row = gid >> 5, lane = gid & 31;
    if (row >= NN) return;
    int a0 = rowoffs[NR + row], a1 = rowoffs[NR + row + 1];
    int b0 = rowoffs[2 * NR + row], b1 = rowoffs[2 * NR + row + 1];
    float s10 = 0.f, s11 = 0.f, s20 = 0.f, s21 = 0.f;
    for (int j = a0; j < a1; j++) {
        uint u = T1[(size_t)csr[j] * 32 + lane];
        s10 += bf2f(u & 0xffffu);
        s11 += bf2f(u >> 16);
    }
    for (int j = b0; j < b1; j++) {
        uint u = T2[(size_t)csr[j] * 32 + lane];
        s20 += bf2f(u & 0xffffu);
        s21 += bf2f(u >> 16);
    }
    int d1 = a1 - a0, d2 = b1 - b0;
    float i1 = 1.f / (float)(d1 > 1 ? d1 : 1);
    float i2 = 1.f / (float)(d2 > 1 ? d2 : 1);
    uint dd = D0[(size_t)row * 32 + lane];
    float* yr = y0 + (size_t)row * 64 + lane * 2;
    yr[0] = bf2f(dd & 0xffffu) + 0.5f * (s10 * i1 + s20 * i2) + by[lane * 2];
    yr[1] = bf2f(dd >> 16) + 0.5f * (s11 * i1 + s21 * i2) + by[lane * 2 + 1];
}

// ---------------- batch-norm stats ----------------
__global__ __launch_bounds__(256) void bn_stats_kernel(
    const float* __restrict__ y0, const float* __restrict__ y1,
    float* __restrict__ accbase) {
    const float* __restrict__ y = blockIdx.y ? y1 : y0;
    float* __restrict__ acc = accbase + blockIdx.y * 128;
    const int col = threadIdx.x & 63, rg = threadIdx.x >> 6;
    float s = 0.f, q = 0.f;
    for (int r = blockIdx.x * 4 + rg; r < NN; r += 256 * 4) {
        float v = y[(size_t)r * 64 + col];
        s += v;
        q = fmaf(v, v, q);
    }
    __shared__ float ls[4][64], lq[4][64];
    ls[rg][col] = s;
    lq[rg][col] = q;
    __syncthreads();
    if (rg == 0) {
        s = ls[0][col] + ls[1][col] + ls[2][col] + ls[3][col];
        q = lq[0][col] + lq[1][col] + lq[2][col] + lq[3][col];
        atomicAdd(&acc[col], s);
        atomicAdd(&acc[64 + col], q);
    }
}

__global__ void bn_fin_kernel(const float* __restrict__ acc,
                              const float* __restrict__ gamma,
                              const float* __restrict__ beta,
                              float* __restrict__ bnss, int l) {
    int t = threadIdx.x;
    if (t >= 128) return;
    int ty = t >> 6, c = t & 63;
    int idx = l * 2 + ty;
    const float invn = 1.0f / (float)NN;
    float mean = acc[idx * 128 + c] * invn;
    float msq = acc[idx * 128 + 64 + c] * invn;
    float var = msq - mean * mean;
    float rs = 1.0f / sqrtf(var + 1.0f);   // eps = 1.0 per reference
    float scv = rs * gamma[idx * 64 + c];
    bnss[idx * 128 + c] = scv;
    bnss[idx * 128 + 64 + c] = beta[idx * 64 + c] - mean * scv;
}

// ---------------- head: out = leaky(bn(y)) @ Wp + bp ----------------
__global__ __launch_bounds__(256) void head_kernel(
    const float* __restrict__ y0, const float* __restrict__ y1,
    const float* __restrict__ Wp, const float* __restrict__ bp,
    const float* __restrict__ ssb, float* __restrict__ outb) {
    constexpr int KPH = 68;
    __shared__ float lw[512];
    __shared__ float la[64 * KPH];
    const int ty = blockIdx.y;
    const float* __restrict__ A = ty ? y1 : y0;
    const float* __restrict__ ss = ssb + ty * 128;
    float* __restrict__ out = outb + (size_t)ty * (NN * 8);
    const int t = threadIdx.x;
    for (int i = t; i < 512; i += 256) lw[i] = Wp[ty * 512 + i];
    const int col = t & 63, rg = t >> 6;
    const float sc = ss[col], sh = ss[64 + col];
    const int base = blockIdx.x * 64;
    const int swz = (col & 3) << 3;
#pragma unroll
    for (int i = 0; i < 16; i++) {
        int r = rg * 16 + i;
        int grow = base + r;
        float v = 0.f;
        if (grow < NN) {
            v = A[(size_t)grow * 64 + col];
            v = fmaf(v, sc, sh);
            v = (v >= 0.f) ? v : 0.01f * v;
        }
        la[col * KPH + (r ^ swz)] = v;
    }
    __syncthreads();
    const int c = t & 7, rp = t >> 3;
    float o0 = 0.f, o1 = 0.f;
#pragma unroll
    for (int k = 0; k < 64; k++) {
        float w = lw[k * 8 + c];
        int pos = k * KPH + ((rp * 2) ^ ((k & 3) << 3));
        o0 = fmaf(la[pos], w, o0);
        o1 = fmaf(la[pos + 1], w, o1);
    }
    float b = bp[ty * 8 + c];
    int g0 = base + rp * 2;
    if (g0 < NN) out[(size_t)g0 * 8 + c] = o0 + b;
    if (g0 + 1 < NN) out[(size_t)(g0 + 1) * 8 + c] = o1 + b;
}

// ---------------- launch ----------------
extern "C" void kernel_launch(void* const* d_in, const int* in_sizes, int n_in,
                              void* d_out, int out_size, void* d_ws, size_t ws_size,
                              hipStream_t stream) {
    const float* x0 = (const float*)d_in[0];
    const float* x1 = (const float*)d_in[1];
    const int* e0 = (const int*)d_in[2];
    const int* e1 = (const int*)d_in[3];
    const int* e2 = (const int*)d_in[4];
    const float* Wsrc = (const float*)d_in[5];
    const float* bsrc = (const float*)d_in[6];
    const float* Wdst = (const float*)d_in[7];
    const float* bdst = (const float*)d_in[8];
    const float* Wupd = (const float*)d_in[9];
    const float* bupd = (const float*)d_in[10];
    const float* gamma = (const float*)d_in[11];
    const float* beta = (const float*)d_in[12];
    const float* Wp = (const float*)d_in[13];
    const float* bp = (const float*)d_in[14];
    float* outp = (float*)d_out;

    // workspace layout (~142 MB)
    uint* Tb = (uint*)d_ws;               // 5 bf16 buffers [N,64]: 5*NH/2 uints
    float* y0 = (float*)(Tb + 5 * (NH / 2));
    float* y1 = y0 + NH;
    float* Weff = y1 + NH;                // 2*5*4096 = 40960
    float* by1p = Weff + 40960;           // 128
    float* by0p = by1p + 128;             // 128
    float* bnacc = by0p + 128;            // 512
    float* bnss = bnacc + 512;            // 512
    int* bh = (int*)(bnss + 512);         // NBT
    int* boffs = bh + NBT;                // NBT + 1
    int* bcur = boffs + NBT + 1;          // NBT
    int* rowoffs = bcur + NBT;            // 3*NR + 1
    int* csr = rowoffs + 3 * NR + 1;      // 3E sorted src ids
    uint* be = (uint*)(csr + 3 * NE);     // 3E packed bucketed edges
    (void)in_sizes; (void)n_in; (void)out_size; (void)ws_size;

    const uint* T0 = Tb;
    const uint* T1 = Tb + 1 * (NH / 2);
    const uint* T2 = Tb + 2 * (NH / 2);
    const uint* D0 = Tb + 3 * (NH / 2);
    const uint* D1 = Tb + 4 * (NH / 2);

    // ---- bucket build + sort + weight prep ----
    zero_kernel<<<19, 256, 0, stream>>>(bh, bnacc);
    prep_kernel<<<161, 256, 0, stream>>>(Wsrc, bsrc, Wdst, bdst, Wupd, bupd,
                                         Weff, by1p, by0p);
    bhist_kernel<<<dim3(128, 3), 256, 0, stream>>>(e0, e1, e2, bh);
    bscan_kernel<<<1, 256, 0, stream>>>(bh, boffs, bcur);
    bscat_kernel<<<dim3(3907, 3), 256, 0, stream>>>(e0, e1, e2, bcur, be);
    bsort_kernel<<<dim3(NB, 3), 256, 0, stream>>>(boffs, be, csr, rowoffs);

    // ---- layer 0 ----
    gemmA_kernel<false><<<dim3(782, 2), 256, 0, stream>>>(x0, x1, Weff, nullptr,
                                                          nullptr, Tb);
    agg_y1_kernel<<<12500, 256, 0, stream>>>(T0, D1, rowoffs, csr, by1p, y1);
    agg_y0_kernel<<<12500, 256, 0, stream>>>(T1, T2, D0, rowoffs, csr, by0p, y0);
    bn_stats_kernel<<<dim3(256, 2), 256, 0, stream>>>(y0, y1, bnacc);
    bn_fin_kernel<<<1, 128, 0, stream>>>(bnacc, gamma, beta, bnss, 0);

    // ---- layer 1 (BN+leaky fused into GEMM loads) ----
    gemmA_kernel<true><<<dim3(782, 2), 256, 0, stream>>>(y0, y1, Weff + 20480,
                                                         bnss, bnss + 128, Tb);
    agg_y1_kernel<<<12500, 256, 0, stream>>>(T0, D1, rowoffs, csr, by1p + 64, y1);
    agg_y0_kernel<<<12500, 256, 0, stream>>>(T1, T2, D0, rowoffs, csr, by0p + 64, y0);
    bn_stats_kernel<<<dim3(256, 2), 256, 0, stream>>>(y0, y1, bnacc + 256);
    bn_fin_kernel<<<1, 128, 0, stream>>>(bnacc, gamma, beta, bnss, 1);

    // ---- heads (BN+leaky fused) ----
    head_kernel<<<dim3(1563, 2), 256, 0, stream>>>(y0, y1, Wp, bp, bnss + 256, outp);
}

// Round 8
// 957.973 us; speedup vs baseline: 3.1716x; 1.2805x over previous
//
#include <hip/hip_runtime.h>
#include <hip/hip_bf16.h>

// HeteroGNN fused pipeline for MI355X.
// N=100000 nodes/type, E=1000000 edges/type, H=64, L=8.
#define NN 100000
#define NE 1000000
#define NH 6400000      // N*H elements per [N,64] buffer
#define NB 1563         // dst-buckets per message type (dst>>6; 1563*64 = 100032)
#define NBT (3 * NB)    // total buckets
#define NR 100032       // padded rows per type (rowoffs stride)
#define PBLK 32         // partition blocks per message type
#define CHUNK (NE / PBLK)   // 31250 edges per partition block

typedef unsigned int uint;
typedef unsigned short ushort;

// bf16 helpers (RNE)
static __device__ inline ushort f2bf(float x) {
    uint u = __float_as_uint(x);
    u = u + 0x7fffu + ((u >> 16) & 1u);
    return (ushort)(u >> 16);
}
static __device__ inline float bf2f(uint h) {   // low 16 bits hold bf16
    return __uint_as_float(h << 16);
}
static __device__ inline uint pack2(float lo, float hi) {
    return (uint)f2bf(lo) | ((uint)f2bf(hi) << 16);
}

// ---------------- zero scratch ----------------
__global__ __launch_bounds__(256) void zero_kernel(float* __restrict__ bnacc) {
    int i = blockIdx.x * 256 + threadIdx.x;
    if (i < 512) bnacc[i] = 0.f;
}

// ---------------- precompute effective weights ----------------
// Weff layout: [layer][which][64][64], which: 0=Ws_eff(m0) 1=Ws_eff(m1) 2=Ws_eff(m2)
//              3=0.5*(Wd_eff(m1)+Wd_eff(m2)) 4=Wd_eff(m0)
__global__ __launch_bounds__(256) void prep_kernel(
    const float* __restrict__ Wsrc, const float* __restrict__ bsrc,
    const float* __restrict__ Wdst, const float* __restrict__ bdst,
    const float* __restrict__ Wupd, const float* __restrict__ bupd,
    float* __restrict__ Weff, float* __restrict__ by1, float* __restrict__ by0) {
    int t = blockIdx.x * 256 + threadIdx.x;
    if (t < 2 * 5 * 4096) {
        int l = t / 20480;
        int rem = t % 20480;
        int which = rem / 4096;
        int kc = rem % 4096;
        int k = kc >> 6, c = kc & 63;
        float v = 0.f;
        if (which < 3) {
            int m = which;
            const float* ws = Wsrc + (l * 3 + m) * 4096 + k * 64;
            const float* wu = Wupd + (l * 3 + m) * 8192 + 64 * 64 + c;  // bottom half rows
            for (int k2 = 0; k2 < 64; k2++) v = fmaf(ws[k2], wu[k2 * 64], v);
        } else if (which == 3) {
            const float* wd1 = Wdst + (l * 3 + 1) * 4096 + k * 64;
            const float* wu1 = Wupd + (l * 3 + 1) * 8192 + c;           // top half rows
            const float* wd2 = Wdst + (l * 3 + 2) * 4096 + k * 64;
            const float* wu2 = Wupd + (l * 3 + 2) * 8192 + c;
            for (int k2 = 0; k2 < 64; k2++)
                v += 0.5f * (wd1[k2] * wu1[k2 * 64] + wd2[k2] * wu2[k2 * 64]);
        } else {
            const float* wd = Wdst + (l * 3 + 0) * 4096 + k * 64;
            const float* wu = Wupd + (l * 3 + 0) * 8192 + c;
            for (int k2 = 0; k2 < 64; k2++) v = fmaf(wd[k2], wu[k2 * 64], v);
        }
        Weff[t] = v;
        return;
    }
    t -= 2 * 5 * 4096;
    if (t < 128) {  // by1: full b_eff of message type 0
        int l = t >> 6, c = t & 63;
        const float* wu = Wupd + (l * 3 + 0) * 8192;
        float v = bupd[(l * 3 + 0) * 64 + c];
        for (int k = 0; k < 64; k++) {
            v = fmaf(bdst[(l * 3 + 0) * 64 + k], wu[k * 64 + c], v);
            v = fmaf(bsrc[(l * 3 + 0) * 64 + k], wu[(64 + k) * 64 + c], v);
        }
        by1[l * 64 + c] = v;
        return;
    }
    t -= 128;
    if (t < 128) {  // by0 = 0.5*(b_eff(m1)+b_eff(m2))
        int l = t >> 6, c = t & 63;
        float v = 0.f;
        for (int m = 1; m <= 2; m++) {
            const float* wu = Wupd + (l * 3 + m) * 8192;
            float s = bupd[(l * 3 + m) * 64 + c];
            for (int k = 0; k < 64; k++) {
                s = fmaf(bdst[(l * 3 + m) * 64 + k], wu[k * 64 + c], s);
                s = fmaf(bsrc[(l * 3 + m) * 64 + k], wu[(64 + k) * 64 + c], s);
            }
            v += 0.5f * s;
        }
        by0[l * 64 + c] = v;
    }
}

// ---------------- pass 1: per-(block,bucket) histogram, no global atomics ----
// grid (PBLK, 3). cnt layout: [ty][blk][NB].
__global__ __launch_bounds__(256) void bhist2_kernel(
    const int* __restrict__ e0, const int* __restrict__ e1,
    const int* __restrict__ e2, int* __restrict__ cnt) {
    __shared__ int lh[NB];
    const int t = threadIdx.x;
    const int blk = blockIdx.x, ty = blockIdx.y;
    const int* __restrict__ ed = ((ty == 0) ? e0 : (ty == 1) ? e1 : e2) + NE;
    for (int i = t; i < NB; i += 256) lh[i] = 0;
    __syncthreads();
    const int cbase = blk * CHUNK;
    for (int i = cbase + t; i < cbase + CHUNK; i += 256)
        atomicAdd(&lh[ed[i] >> 6], 1);
    __syncthreads();
    int* __restrict__ out = cnt + (ty * PBLK + blk) * NB;
    for (int i = t; i < NB; i += 256) out[i] = lh[i];
}

// ---------------- column sum: tot[b] = sum over blocks ----------------
__global__ __launch_bounds__(256) void colsum_kernel(const int* __restrict__ cnt,
                                                     int* __restrict__ tot) {
    int i = blockIdx.x * 256 + threadIdx.x;
    if (i >= NBT) return;
    int ty = i / NB, b = i % NB;
    const int* base = cnt + ty * PBLK * NB + b;
    int s = 0;
#pragma unroll 8
    for (int blk = 0; blk < PBLK; blk++) s += base[blk * NB];
    tot[i] = s;
}

// ---------------- bucket scan (one block over 4689 bins) ----------------
__global__ __launch_bounds__(256) void bscan_kernel(const int* __restrict__ tot,
                                                    int* __restrict__ boffs) {
    __shared__ int s[256];
    __shared__ int carry;
    const int t = threadIdx.x;
    if (t == 0) carry = 0;
    __syncthreads();
    for (int base = 0; base < NBT; base += 256) {
        int i = base + t;
        int v = (i < NBT) ? tot[i] : 0;
        s[t] = v;
        __syncthreads();
        for (int d = 1; d < 256; d <<= 1) {
            int tv = (t >= d) ? s[t - d] : 0;
            __syncthreads();
            s[t] += tv;
            __syncthreads();
        }
        if (i < NBT) boffs[i] = s[t] - v + carry;
        __syncthreads();
        if (t == 0) carry += s[255];
        __syncthreads();
    }
    if (t == 0) boffs[NBT] = 3 * NE;
}

// ---------------- column prefix: blkoff[ty][blk][b] ----------------
__global__ __launch_bounds__(256) void colpre_kernel(const int* __restrict__ cnt,
                                                     const int* __restrict__ boffs,
                                                     int* __restrict__ blkoff) {
    int i = blockIdx.x * 256 + threadIdx.x;
    if (i >= NBT) return;
    int ty = i / NB, b = i % NB;
    int run = boffs[i];
    const int* cbase = cnt + ty * PBLK * NB + b;
    int* obase = blkoff + ty * PBLK * NB + b;
#pragma unroll 8
    for (int blk = 0; blk < PBLK; blk++) {
        obase[blk * NB] = run;
        run += cbase[blk * NB];
    }
}

// ---------------- pass 2: partition into private windows (LDS cursors) ----
// grid (PBLK, 3). Each block appends ONLY into its own (blk,bucket) windows ->
// cache lines have a single writer (no cross-XCD ping-pong, no global atomics).
__global__ __launch_bounds__(256) void bscat2_kernel(
    const int* __restrict__ e0, const int* __restrict__ e1,
    const int* __restrict__ e2, const int* __restrict__ blkoff,
    uint* __restrict__ be) {
    __shared__ int cursor[NB];
    const int t = threadIdx.x;
    const int blk = blockIdx.x, ty = blockIdx.y;
    const int* __restrict__ e = (ty == 0) ? e0 : (ty == 1) ? e1 : e2;
    const int* __restrict__ cb = blkoff + (ty * PBLK + blk) * NB;
    for (int i = t; i < NB; i += 256) cursor[i] = cb[i];
    __syncthreads();
    const int cbase = blk * CHUNK;
    for (int i = cbase + t; i < cbase + CHUNK; i += 256) {
        int s = e[i], d = e[NE + i];
        int pos = atomicAdd(&cursor[d >> 6], 1);
        be[pos] = ((uint)(d & 63) << 17) | (uint)s;
    }
}

// ---------------- per-bucket counting sort -> dst-sorted CSR + row offsets ----
__global__ __launch_bounds__(256) void bsort_kernel(
    const int* __restrict__ boffs, const uint* __restrict__ be,
    int* __restrict__ csr, int* __restrict__ rowoffs) {
    __shared__ int cnt[64];
    __shared__ int pre[64];
    __shared__ int cur[64];
    const int t = threadIdx.x;
    const int ty = blockIdx.y;
    const int g = ty * NB + blockIdx.x;
    const int o0 = boffs[g], o1 = boffs[g + 1];
    if (t < 64) cnt[t] = 0;
    __syncthreads();
    for (int j = o0 + t; j < o1; j += 256) atomicAdd(&cnt[be[j] >> 17], 1);
    __syncthreads();
    if (t == 0) {
        int run = o0;
        for (int i = 0; i < 64; i++) { pre[i] = run; run += cnt[i]; }
    }
    __syncthreads();
    if (t < 64) {
        cur[t] = pre[t];
        rowoffs[ty * NR + blockIdx.x * 64 + t] = pre[t];
    }
    __syncthreads();
    for (int j = o0 + t; j < o1; j += 256) {
        uint pk = be[j];
        int pos = atomicAdd(&cur[pk >> 17], 1);
        csr[pos] = (int)(pk & 0x1ffffu);
    }
}

// ---------------- fused multi-output GEMM ----------------
// grid (782, 2). ty=0: A = x0-type, outputs {0,2,3}; ty=1: A = x1-type, {1,4}.
// A-tile staged once in LDS [128][65]; outputs stored bf16 (full-line stores).
template <bool BN>
__global__ __launch_bounds__(256) void gemmA_kernel(
    const float* __restrict__ x0, const float* __restrict__ x1,
    const float* __restrict__ Weff, const float* __restrict__ ss0,
    const float* __restrict__ ss1, uint* __restrict__ Tb) {
    __shared__ float la[128 * 65];
    const int ty = blockIdx.y;
    const float* __restrict__ A = ty ? x1 : x0;
    const float* __restrict__ ss = ty ? ss1 : ss0;
    const int t = threadIdx.x;
    const int base = blockIdx.x * 128;
#pragma unroll
    for (int i = 0; i < 8; i++) {
        int chunk = i * 256 + t;
        int r = chunk >> 4, c4 = chunk & 15;
        int grow = base + r;
        float4 v = make_float4(0.f, 0.f, 0.f, 0.f);
        if (grow < NN)
            v = *reinterpret_cast<const float4*>(A + (size_t)grow * 64 + c4 * 4);
        if (BN) {
            float4 sc = *reinterpret_cast<const float4*>(ss + c4 * 4);
            float4 sh = *reinterpret_cast<const float4*>(ss + 64 + c4 * 4);
            v.x = fmaf(v.x, sc.x, sh.x); v.x = v.x >= 0.f ? v.x : 0.01f * v.x;
            v.y = fmaf(v.y, sc.y, sh.y); v.y = v.y >= 0.f ? v.y : 0.01f * v.y;
            v.z = fmaf(v.z, sc.z, sh.z); v.z = v.z >= 0.f ? v.z : 0.01f * v.z;
            v.w = fmaf(v.w, sc.w, sh.w); v.w = v.w >= 0.f ? v.w : 0.01f * v.w;
        }
        int lb = r * 65 + c4 * 4;
        la[lb] = v.x; la[lb + 1] = v.y; la[lb + 2] = v.z; la[lb + 3] = v.w;
    }
    __syncthreads();
    const int cg = t & 7, rr = t >> 3;
    const int rb = rr * 4 * 65;
    const int nout = ty ? 2 : 3;
#pragma unroll
    for (int o = 0; o < 3; o++) {
        if (o >= nout) break;
        const int which = ty ? (o == 0 ? 1 : 4) : (o == 0 ? 0 : (o == 1 ? 2 : 3));
        const float* __restrict__ W = Weff + which * 4096;
        float4 a0c[4], a1c[4];
#pragma unroll
        for (int j = 0; j < 4; j++) {
            a0c[j] = make_float4(0.f, 0.f, 0.f, 0.f);
            a1c[j] = make_float4(0.f, 0.f, 0.f, 0.f);
        }
#pragma unroll 8
        for (int k = 0; k < 64; k++) {
            float a0 = la[rb + k];
            float a1 = la[rb + 65 + k];
            float a2 = la[rb + 130 + k];
            float a3 = la[rb + 195 + k];
            const float4* w4 = reinterpret_cast<const float4*>(W + k * 64 + cg * 8);
            float4 w0 = w4[0], w1 = w4[1];
            a0c[0].x = fmaf(a0, w0.x, a0c[0].x); a0c[0].y = fmaf(a0, w0.y, a0c[0].y);
            a0c[0].z = fmaf(a0, w0.z, a0c[0].z); a0c[0].w = fmaf(a0, w0.w, a0c[0].w);
            a1c[0].x = fmaf(a0, w1.x, a1c[0].x); a1c[0].y = fmaf(a0, w1.y, a1c[0].y);
            a1c[0].z = fmaf(a0, w1.z, a1c[0].z); a1c[0].w = fmaf(a0, w1.w, a1c[0].w);
            a0c[1].x = fmaf(a1, w0.x, a0c[1].x); a0c[1].y = fmaf(a1, w0.y, a0c[1].y);
            a0c[1].z = fmaf(a1, w0.z, a0c[1].z); a0c[1].w = fmaf(a1, w0.w, a0c[1].w);
            a1c[1].x = fmaf(a1, w1.x, a1c[1].x); a1c[1].y = fmaf(a1, w1.y, a1c[1].y);
            a1c[1].z = fmaf(a1, w1.z, a1c[1].z); a1c[1].w = fmaf(a1, w1.w, a1c[1].w);
            a0c[2].x = fmaf(a2, w0.x, a0c[2].x); a0c[2].y = fmaf(a2, w0.y, a0c[2].y);
            a0c[2].z = fmaf(a2, w0.z, a0c[2].z); a0c[2].w = fmaf(a2, w0.w, a0c[2].w);
            a1c[2].x = fmaf(a2, w1.x, a1c[2].x); a1c[2].y = fmaf(a2, w1.y, a1c[2].y);
            a1c[2].z = fmaf(a2, w1.z, a1c[2].z); a1c[2].w = fmaf(a2, w1.w, a1c[2].w);
            a0c[3].x = fmaf(a3, w0.x, a0c[3].x); a0c[3].y = fmaf(a3, w0.y, a0c[3].y);
            a0c[3].z = fmaf(a3, w0.z, a0c[3].z); a0c[3].w = fmaf(a3, w0.w, a0c[3].w);
            a1c[3].x = fmaf(a3, w1.x, a1c[3].x); a1c[3].y = fmaf(a3, w1.y, a1c[3].y);
            a1c[3].z = fmaf(a3, w1.z, a1c[3].z); a1c[3].w = fmaf(a3, w1.w, a1c[3].w);
        }
        uint* __restrict__ out = Tb + (size_t)which * (NH / 2);
#pragma unroll
        for (int j = 0; j < 4; j++) {
            int grow = base + rr * 4 + j;
            if (grow < NN) {
                uint4 pk;
                pk.x = pack2(a0c[j].x, a0c[j].y);
                pk.y = pack2(a0c[j].z, a0c[j].w);
                pk.z = pack2(a1c[j].x, a1c[j].y);
                pk.w = pack2(a1c[j].z, a1c[j].w);
                *reinterpret_cast<uint4*>(out + (size_t)grow * 32 + cg * 4) = pk;
            }
        }
    }
}

// ---------------- aggregation (CSR mean-gather, bf16 T/D, fp32 y out) ----------------
__global__ __launch_bounds__(256) void agg_y1_kernel(
    const uint* __restrict__ T0, const uint* __restrict__ D1,
    const int* __restrict__ rowoffs, const int* __restrict__ csr,
    const float* __restrict__ by, float* __restrict__ y1) {
    int gid = blockIdx.x * 256 + threadIdx.x;
    int row = gid >> 5, lane = gid & 31;
    if (row >= NN) return;
    int o0 = rowoffs[row], o1 = rowoffs[row + 1];
    float s0 = 0.f, s1 = 0.f;
    for (int j = o0; j < o1; j++) {
        uint u = T0[(size_t)csr[j] * 32 + lane];
        s0 += bf2f(u & 0xffffu);
        s1 += bf2f(u >> 16);
    }
    int d = o1 - o0;
    float inv = 1.f / (float)(d > 1 ? d : 1);
    uint dd = D1[(size_t)row * 32 + lane];
    float* yr = y1 + (size_t)row * 64 + lane * 2;
    yr[0] = bf2f(dd & 0xffffu) + s0 * inv + by[lane * 2];
    yr[1] = bf2f(dd >> 16) + s1 * inv + by[lane * 2 + 1];
}

__global__ __launch_bounds__(256) void agg_y0_kernel(
    const uint* __restrict__ T1, const uint* __restrict__ T2,
    const uint* __restrict__ D0, const int* __restrict__ rowoffs,
    const int* __restrict__ csr, const float* __restrict__ by,
    float* __restrict__ y0) {
    int gid = blockIdx.x * 256 + threadIdx.x;
    int row = gid >> 5, lane = gid & 31;
    if (row >= NN) return;
    int a0 = rowoffs[NR + row], a1 = rowoffs[NR + row + 1];
    int b0 = rowoffs[2 * NR + row], b1 = rowoffs[2 * NR + row + 1];
    float s10 = 0.f, s11 = 0.f, s20 = 0.f, s21 = 0.f;
    for (int j = a0; j < a1; j++) {
        uint u = T1[(size_t)csr[j] * 32 + lane];
        s10 += bf2f(u & 0xffffu);
        s11 += bf2f(u >> 16);
    }
    for (int j = b0; j < b1; j++) {
        uint u = T2[(size_t)csr[j] * 32 + lane];
        s20 += bf2f(u & 0xffffu);
        s21 += bf2f(u >> 16);
    }
    int d1 = a1 - a0, d2 = b1 - b0;
    float i1 = 1.f / (float)(d1 > 1 ? d1 : 1);
    float i2 = 1.f / (float)(d2 > 1 ? d2 : 1);
    uint dd = D0[(size_t)row * 32 + lane];
    float* yr = y0 + (size_t)row * 64 + lane * 2;
    yr[0] = bf2f(dd & 0xffffu) + 0.5f * (s10 * i1 + s20 * i2) + by[lane * 2];
    yr[1] = bf2f(dd >> 16) + 0.5f * (s11 * i1 + s21 * i2) + by[lane * 2 + 1];
}

// ---------------- batch-norm stats ----------------
__global__ __launch_bounds__(256) void bn_stats_kernel(
    const float* __restrict__ y0, const float* __restrict__ y1,
    float* __restrict__ accbase) {
    const float* __restrict__ y = blockIdx.y ? y1 : y0;
    float* __restrict__ acc = accbase + blockIdx.y * 128;
    const int col = threadIdx.x & 63, rg = threadIdx.x >> 6;
    float s = 0.f, q = 0.f;
    for (int r = blockIdx.x * 4 + rg; r < NN; r += 256 * 4) {
        float v = y[(size_t)r * 64 + col];
        s += v;
        q = fmaf(v, v, q);
    }
    __shared__ float ls[4][64], lq[4][64];
    ls[rg][col] = s;
    lq[rg][col] = q;
    __syncthreads();
    if (rg == 0) {
        s = ls[0][col] + ls[1][col] + ls[2][col] + ls[3][col];
        q = lq[0][col] + lq[1][col] + lq[2][col] + lq[3][col];
        atomicAdd(&acc[col], s);
        atomicAdd(&acc[64 + col], q);
    }
}

__global__ void bn_fin_kernel(const float* __restrict__ acc,
                              const float* __restrict__ gamma,
                              const float* __restrict__ beta,
                              float* __restrict__ bnss, int l) {
    int t = threadIdx.x;
    if (t >= 128) return;
    int ty = t >> 6, c = t & 63;
    int idx = l * 2 + ty;
    const float invn = 1.0f / (float)NN;
    float mean = acc[idx * 128 + c] * invn;
    float msq = acc[idx * 128 + 64 + c] * invn;
    float var = msq - mean * mean;
    float rs = 1.0f / sqrtf(var + 1.0f);   // eps = 1.0 per reference
    float scv = rs * gamma[idx * 64 + c];
    bnss[idx * 128 + c] = scv;
    bnss[idx * 128 + 64 + c] = beta[idx * 64 + c] - mean * scv;
}

// ---------------- head: out = leaky(bn(y)) @ Wp + bp ----------------
__global__ __launch_bounds__(256) void head_kernel(
    const float* __restrict__ y0, const float* __restrict__ y1,
    const float* __restrict__ Wp, const float* __restrict__ bp,
    const float* __restrict__ ssb, float* __restrict__ outb) {
    constexpr int KPH = 68;
    __shared__ float lw[512];
    __shared__ float la[64 * KPH];
    const int ty = blockIdx.y;
    const float* __restrict__ A = ty ? y1 : y0;
    const float* __restrict__ ss = ssb + ty * 128;
    float* __restrict__ out = outb + (size_t)ty * (NN * 8);
    const int t = threadIdx.x;
    for (int i = t; i < 512; i += 256) lw[i] = Wp[ty * 512 + i];
    const int col = t & 63, rg = t >> 6;
    const float sc = ss[col], sh = ss[64 + col];
    const int base = blockIdx.x * 64;
    const int swz = (col & 3) << 3;
#pragma unroll
    for (int i = 0; i < 16; i++) {
        int r = rg * 16 + i;
        int grow = base + r;
        float v = 0.f;
        if (grow < NN) {
            v = A[(size_t)grow * 64 + col];
            v = fmaf(v, sc, sh);
            v = (v >= 0.f) ? v : 0.01f * v;
        }
        la[col * KPH + (r ^ swz)] = v;
    }
    __syncthreads();
    const int c = t & 7, rp = t >> 3;
    float o0 = 0.f, o1 = 0.f;
#pragma unroll
    for (int k = 0; k < 64; k++) {
        float w = lw[k * 8 + c];
        int pos = k * KPH + ((rp * 2) ^ ((k & 3) << 3));
        o0 = fmaf(la[pos], w, o0);
        o1 = fmaf(la[pos + 1], w, o1);
    }
    float b = bp[ty * 8 + c];
    int g0 = base + rp * 2;
    if (g0 < NN) out[(size_t)g0 * 8 + c] = o0 + b;
    if (g0 + 1 < NN) out[(size_t)(g0 + 1) * 8 + c] = o1 + b;
}

// ---------------- launch ----------------
extern "C" void kernel_launch(void* const* d_in, const int* in_sizes, int n_in,
                              void* d_out, int out_size, void* d_ws, size_t ws_size,
                              hipStream_t stream) {
    const float* x0 = (const float*)d_in[0];
    const float* x1 = (const float*)d_in[1];
    const int* e0 = (const int*)d_in[2];
    const int* e1 = (const int*)d_in[3];
    const int* e2 = (const int*)d_in[4];
    const float* Wsrc = (const float*)d_in[5];
    const float* bsrc = (const float*)d_in[6];
    const float* Wdst = (const float*)d_in[7];
    const float* bdst = (const float*)d_in[8];
    const float* Wupd = (const float*)d_in[9];
    const float* bupd = (const float*)d_in[10];
    const float* gamma = (const float*)d_in[11];
    const float* beta = (const float*)d_in[12];
    const float* Wp = (const float*)d_in[13];
    const float* bp = (const float*)d_in[14];
    float* outp = (float*)d_out;

    // workspace layout (~145 MB)
    uint* Tb = (uint*)d_ws;               // 5 bf16 buffers [N,64]: 5*NH/2 uints
    float* y0 = (float*)(Tb + 5 * (NH / 2));
    float* y1 = y0 + NH;
    float* Weff = y1 + NH;                // 2*5*4096 = 40960
    float* by1p = Weff + 40960;           // 128
    float* by0p = by1p + 128;             // 128
    float* bnacc = by0p + 128;            // 512
    float* bnss = bnacc + 512;            // 512
    int* cnt = (int*)(bnss + 512);        // 3*PBLK*NB = 150048
    int* tot = cnt + 3 * PBLK * NB;       // NBT
    int* boffs = tot + NBT;               // NBT + 1
    int* blkoff = boffs + NBT + 1;        // 3*PBLK*NB
    int* rowoffs = blkoff + 3 * PBLK * NB;// 3*NR + 1
    int* csr = rowoffs + 3 * NR + 1;      // 3E sorted src ids
    uint* be = (uint*)(csr + 3 * NE);     // 3E packed bucketed edges
    (void)in_sizes; (void)n_in; (void)out_size; (void)ws_size;

    const uint* T0 = Tb;
    const uint* T1 = Tb + 1 * (NH / 2);
    const uint* T2 = Tb + 2 * (NH / 2);
    const uint* D0 = Tb + 3 * (NH / 2);
    const uint* D1 = Tb + 4 * (NH / 2);

    // ---- deterministic partition (no global atomics) + sort + weight prep ----
    zero_kernel<<<2, 256, 0, stream>>>(bnacc);
    prep_kernel<<<161, 256, 0, stream>>>(Wsrc, bsrc, Wdst, bdst, Wupd, bupd,
                                         Weff, by1p, by0p);
    bhist2_kernel<<<dim3(PBLK, 3), 256, 0, stream>>>(e0, e1, e2, cnt);
    colsum_kernel<<<19, 256, 0, stream>>>(cnt, tot);
    bscan_kernel<<<1, 256, 0, stream>>>(tot, boffs);
    colpre_kernel<<<19, 256, 0, stream>>>(cnt, boffs, blkoff);
    bscat2_kernel<<<dim3(PBLK, 3), 256, 0, stream>>>(e0, e1, e2, blkoff, be);
    bsort_kernel<<<dim3(NB, 3), 256, 0, stream>>>(boffs, be, csr, rowoffs);

    // ---- layer 0 ----
    gemmA_kernel<false><<<dim3(782, 2), 256, 0, stream>>>(x0, x1, Weff, nullptr,
                                                          nullptr, Tb);
    agg_y1_kernel<<<12500, 256, 0, stream>>>(T0, D1, rowoffs, csr, by1p, y1);
    agg_y0_kernel<<<12500, 256, 0, stream>>>(T1, T2, D0, rowoffs, csr, by0p, y0);
    bn_stats_kernel<<<dim3(256, 2), 256, 0, stream>>>(y0, y1, bnacc);
    bn_fin_kernel<<<1, 128, 0, stream>>>(bnacc, gamma, beta, bnss, 0);

    // ---- layer 1 (BN+leaky fused into GEMM loads) ----
    gemmA_kernel<true><<<dim3(782, 2), 256, 0, stream>>>(y0, y1, Weff + 20480,
                                                         bnss, bnss + 128, Tb);
    agg_y1_kernel<<<12500, 256, 0, stream>>>(T0, D1, rowoffs, csr, by1p + 64, y1);
    agg_y0_kernel<<<12500, 256, 0, stream>>>(T1, T2, D0, rowoffs, csr, by0p + 64, y0);
    bn_stats_kernel<<<dim3(256, 2), 256, 0, stream>>>(y0, y1, bnacc + 256);
    bn_fin_kernel<<<1, 128, 0, stream>>>(bnacc, gamma, beta, bnss, 1);

    // ---- heads (BN+leaky fused) ----
    head_kernel<<<dim3(1563, 2), 256, 0, stream>>>(y0, y1, Wp, bp, bnss + 256, outp);
}

// Round 10
// 796.899 us; speedup vs baseline: 3.8127x; 1.2021x over previous
//
#include <hip/hip_runtime.h>
#include <hip/hip_bf16.h>

// HeteroGNN fused pipeline for MI355X.
// N=100000 nodes/type, E=1000000 edges/type, H=64, L=8.
#define NN 100000
#define NE 1000000
#define NH 6400000      // N*H elements per [N,64] buffer
#define NB 1563         // dst-buckets per message type (dst>>6; 1563*64 = 100032)
#define NBT (3 * NB)    // total buckets
#define NR 100032       // padded rows per type (rowoffs stride)
#define PBLK 32         // partition blocks per message type
#define CHUNK (NE / PBLK)   // 31250 edges per partition block

typedef unsigned int uint;
typedef unsigned short ushort;

// bf16 helpers (RNE)
static __device__ inline ushort f2bf(float x) {
    uint u = __float_as_uint(x);
    u = u + 0x7fffu + ((u >> 16) & 1u);
    return (ushort)(u >> 16);
}
static __device__ inline float bf2f(uint h) {   // low 16 bits hold bf16
    return __uint_as_float(h << 16);
}
static __device__ inline uint pack2(float lo, float hi) {
    return (uint)f2bf(lo) | ((uint)f2bf(hi) << 16);
}

// 4x-unrolled CSR mean-gather: 4 independent row-loads in flight per thread
// (latency-bound fix: round-8 profile showed VALU 20% / HBM 17% / occ 70% --
// dependent load chain was the limiter).
static __device__ inline void gather4(const uint* __restrict__ T,
                                      const int* __restrict__ csr,
                                      int o0, int o1, int lane,
                                      float& s0, float& s1) {
    int j = o0;
    for (; j + 4 <= o1; j += 4) {
        int i0 = csr[j], i1 = csr[j + 1], i2 = csr[j + 2], i3 = csr[j + 3];
        uint u0 = T[(size_t)i0 * 32 + lane];
        uint u1 = T[(size_t)i1 * 32 + lane];
        uint u2 = T[(size_t)i2 * 32 + lane];
        uint u3 = T[(size_t)i3 * 32 + lane];
        s0 += (bf2f(u0 & 0xffffu) + bf2f(u1 & 0xffffu)) +
              (bf2f(u2 & 0xffffu) + bf2f(u3 & 0xffffu));
        s1 += (bf2f(u0 >> 16) + bf2f(u1 >> 16)) +
              (bf2f(u2 >> 16) + bf2f(u3 >> 16));
    }
    for (; j < o1; j++) {
        uint u = T[(size_t)csr[j] * 32 + lane];
        s0 += bf2f(u & 0xffffu);
        s1 += bf2f(u >> 16);
    }
}

// ---------------- zero scratch ----------------
__global__ __launch_bounds__(256) void zero_kernel(float* __restrict__ bnacc) {
    int i = blockIdx.x * 256 + threadIdx.x;
    if (i < 512) bnacc[i] = 0.f;
}

// ---------------- precompute effective weights ----------------
// Weff layout: [layer][which][64][64], which: 0=Ws_eff(m0) 1=Ws_eff(m1) 2=Ws_eff(m2)
//              3=0.5*(Wd_eff(m1)+Wd_eff(m2)) 4=Wd_eff(m0)
__global__ __launch_bounds__(256) void prep_kernel(
    const float* __restrict__ Wsrc, const float* __restrict__ bsrc,
    const float* __restrict__ Wdst, const float* __restrict__ bdst,
    const float* __restrict__ Wupd, const float* __restrict__ bupd,
    float* __restrict__ Weff, float* __restrict__ by1, float* __restrict__ by0) {
    int t = blockIdx.x * 256 + threadIdx.x;
    if (t < 2 * 5 * 4096) {
        int l = t / 20480;
        int rem = t % 20480;
        int which = rem / 4096;
        int kc = rem % 4096;
        int k = kc >> 6, c = kc & 63;
        float v = 0.f;
        if (which < 3) {
            int m = which;
            const float* ws = Wsrc + (l * 3 + m) * 4096 + k * 64;
            const float* wu = Wupd + (l * 3 + m) * 8192 + 64 * 64 + c;  // bottom half rows
            for (int k2 = 0; k2 < 64; k2++) v = fmaf(ws[k2], wu[k2 * 64], v);
        } else if (which == 3) {
            const float* wd1 = Wdst + (l * 3 + 1) * 4096 + k * 64;
            const float* wu1 = Wupd + (l * 3 + 1) * 8192 + c;           // top half rows
            const float* wd2 = Wdst + (l * 3 + 2) * 4096 + k * 64;
            const float* wu2 = Wupd + (l * 3 + 2) * 8192 + c;
            for (int k2 = 0; k2 < 64; k2++)
                v += 0.5f * (wd1[k2] * wu1[k2 * 64] + wd2[k2] * wu2[k2 * 64]);
        } else {
            const float* wd = Wdst + (l * 3 + 0) * 4096 + k * 64;
            const float* wu = Wupd + (l * 3 + 0) * 8192 + c;
            for (int k2 = 0; k2 < 64; k2++) v = fmaf(wd[k2], wu[k2 * 64], v);
        }
        Weff[t] = v;
        return;
    }
    t -= 2 * 5 * 4096;
    if (t < 128) {  // by1: full b_eff of message type 0
        int l = t >> 6, c = t & 63;
        const float* wu = Wupd + (l * 3 + 0) * 8192;
        float v = bupd[(l * 3 + 0) * 64 + c];
        for (int k = 0; k < 64; k++) {
            v = fmaf(bdst[(l * 3 + 0) * 64 + k], wu[k * 64 + c], v);
            v = fmaf(bsrc[(l * 3 + 0) * 64 + k], wu[(64 + k) * 64 + c], v);
        }
        by1[l * 64 + c] = v;
        return;
    }
    t -= 128;
    if (t < 128) {  // by0 = 0.5*(b_eff(m1)+b_eff(m2))
        int l = t >> 6, c = t & 63;
        float v = 0.f;
        for (int m = 1; m <= 2; m++) {
            const float* wu = Wupd + (l * 3 + m) * 8192;
            float s = bupd[(l * 3 + m) * 64 + c];
            for (int k = 0; k < 64; k++) {
                s = fmaf(bdst[(l * 3 + m) * 64 + k], wu[k * 64 + c], s);
                s = fmaf(bsrc[(l * 3 + m) * 64 + k], wu[(64 + k) * 64 + c], s);
            }
            v += 0.5f * s;
        }
        by0[l * 64 + c] = v;
    }
}

// ---------------- pass 1: per-(block,bucket) histogram, no global atomics ----
// grid (PBLK, 3). cnt layout: [ty][blk][NB].
__global__ __launch_bounds__(256) void bhist2_kernel(
    const int* __restrict__ e0, const int* __restrict__ e1,
    const int* __restrict__ e2, int* __restrict__ cnt) {
    __shared__ int lh[NB];
    const int t = threadIdx.x;
    const int blk = blockIdx.x, ty = blockIdx.y;
    const int* __restrict__ ed = ((ty == 0) ? e0 : (ty == 1) ? e1 : e2) + NE;
    for (int i = t; i < NB; i += 256) lh[i] = 0;
    __syncthreads();
    const int cbase = blk * CHUNK;
    for (int i = cbase + t; i < cbase + CHUNK; i += 256)
        atomicAdd(&lh[ed[i] >> 6], 1);
    __syncthreads();
    int* __restrict__ out = cnt + (ty * PBLK + blk) * NB;
    for (int i = t; i < NB; i += 256) out[i] = lh[i];
}

// ---------------- column sum: tot[b] = sum over blocks ----------------
__global__ __launch_bounds__(256) void colsum_kernel(const int* __restrict__ cnt,
                                                     int* __restrict__ tot) {
    int i = blockIdx.x * 256 + threadIdx.x;
    if (i >= NBT) return;
    int ty = i / NB, b = i % NB;
    const int* base = cnt + ty * PBLK * NB + b;
    int s = 0;
#pragma unroll 8
    for (int blk = 0; blk < PBLK; blk++) s += base[blk * NB];
    tot[i] = s;
}

// ---------------- bucket scan (one block over 4689 bins) ----------------
__global__ __launch_bounds__(256) void bscan_kernel(const int* __restrict__ tot,
                                                    int* __restrict__ boffs) {
    __shared__ int s[256];
    __shared__ int carry;
    const int t = threadIdx.x;
    if (t == 0) carry = 0;
    __syncthreads();
    for (int base = 0; base < NBT; base += 256) {
        int i = base + t;
        int v = (i < NBT) ? tot[i] : 0;
        s[t] = v;
        __syncthreads();
        for (int d = 1; d < 256; d <<= 1) {
            int tv = (t >= d) ? s[t - d] : 0;
            __syncthreads();
            s[t] += tv;
            __syncthreads();
        }
        if (i < NBT) boffs[i] = s[t] - v + carry;
        __syncthreads();
        if (t == 0) carry += s[255];
        __syncthreads();
    }
    if (t == 0) boffs[NBT] = 3 * NE;
}

// ---------------- column prefix: blkoff[ty][blk][b] ----------------
__global__ __launch_bounds__(256) void colpre_kernel(const int* __restrict__ cnt,
                                                     const int* __restrict__ boffs,
                                                     int* __restrict__ blkoff) {
    int i = blockIdx.x * 256 + threadIdx.x;
    if (i >= NBT) return;
    int ty = i / NB, b = i % NB;
    int run = boffs[i];
    const int* cbase = cnt + ty * PBLK * NB + b;
    int* obase = blkoff + ty * PBLK * NB + b;
#pragma unroll 8
    for (int blk = 0; blk < PBLK; blk++) {
        obase[blk * NB] = run;
        run += cbase[blk * NB];
    }
}

// ---------------- pass 2: partition into private windows (LDS cursors) ----
// grid (PBLK, 3). Each block appends ONLY into its own (blk,bucket) windows ->
// cache lines have a single writer (no cross-XCD ping-pong, no global atomics).
__global__ __launch_bounds__(256) void bscat2_kernel(
    const int* __restrict__ e0, const int* __restrict__ e1,
    const int* __restrict__ e2, const int* __restrict__ blkoff,
    uint* __restrict__ be) {
    __shared__ int cursor[NB];
    const int t = threadIdx.x;
    const int blk = blockIdx.x, ty = blockIdx.y;
    const int* __restrict__ e = (ty == 0) ? e0 : (ty == 1) ? e1 : e2;
    const int* __restrict__ cb = blkoff + (ty * PBLK + blk) * NB;
    for (int i = t; i < NB; i += 256) cursor[i] = cb[i];
    __syncthreads();
    const int cbase = blk * CHUNK;
    for (int i = cbase + t; i < cbase + CHUNK; i += 256) {
        int s = e[i], d = e[NE + i];
        int pos = atomicAdd(&cursor[d >> 6], 1);
        be[pos] = ((uint)(d & 63) << 17) | (uint)s;
    }
}

// ---------------- per-bucket counting sort -> dst-sorted CSR + row offsets ----
__global__ __launch_bounds__(256) void bsort_kernel(
    const int* __restrict__ boffs, const uint* __restrict__ be,
    int* __restrict__ csr, int* __restrict__ rowoffs) {
    __shared__ int cnt[64];
    __shared__ int pre[64];
    __shared__ int cur[64];
    const int t = threadIdx.x;
    const int ty = blockIdx.y;
    const int g = ty * NB + blockIdx.x;
    const int o0 = boffs[g], o1 = boffs[g + 1];
    if (t < 64) cnt[t] = 0;
    __syncthreads();
    for (int j = o0 + t; j < o1; j += 256) atomicAdd(&cnt[be[j] >> 17], 1);
    __syncthreads();
    if (t == 0) {
        int run = o0;
        for (int i = 0; i < 64; i++) { pre[i] = run; run += cnt[i]; }
    }
    __syncthreads();
    if (t < 64) {
        cur[t] = pre[t];
        rowoffs[ty * NR + blockIdx.x * 64 + t] = pre[t];
    }
    __syncthreads();
    for (int j = o0 + t; j < o1; j += 256) {
        uint pk = be[j];
        int pos = atomicAdd(&cur[pk >> 17], 1);
        csr[pos] = (int)(pk & 0x1ffffu);
    }
}

// ---------------- fused multi-output GEMM ----------------
// grid (782, 2). ty=0: A = x0-type, outputs {0,2,3}; ty=1: A = x1-type, {1,4}.
// A-tile staged once in LDS [128][65]; outputs stored bf16 (full-line stores).
template <bool BN>
__global__ __launch_bounds__(256) void gemmA_kernel(
    const float* __restrict__ x0, const float* __restrict__ x1,
    const float* __restrict__ Weff, const float* __restrict__ ss0,
    const float* __restrict__ ss1, uint* __restrict__ Tb) {
    __shared__ float la[128 * 65];
    const int ty = blockIdx.y;
    const float* __restrict__ A = ty ? x1 : x0;
    const float* __restrict__ ss = ty ? ss1 : ss0;
    const int t = threadIdx.x;
    const int base = blockIdx.x * 128;
#pragma unroll
    for (int i = 0; i < 8; i++) {
        int chunk = i * 256 + t;
        int r = chunk >> 4, c4 = chunk & 15;
        int grow = base + r;
        float4 v = make_float4(0.f, 0.f, 0.f, 0.f);
        if (grow < NN)
            v = *reinterpret_cast<const float4*>(A + (size_t)grow * 64 + c4 * 4);
        if (BN) {
            float4 sc = *reinterpret_cast<const float4*>(ss + c4 * 4);
            float4 sh = *reinterpret_cast<const float4*>(ss + 64 + c4 * 4);
            v.x = fmaf(v.x, sc.x, sh.x); v.x = v.x >= 0.f ? v.x : 0.01f * v.x;
            v.y = fmaf(v.y, sc.y, sh.y); v.y = v.y >= 0.f ? v.y : 0.01f * v.y;
            v.z = fmaf(v.z, sc.z, sh.z); v.z = v.z >= 0.f ? v.z : 0.01f * v.z;
            v.w = fmaf(v.w, sc.w, sh.w); v.w = v.w >= 0.f ? v.w : 0.01f * v.w;
        }
        int lb = r * 65 + c4 * 4;
        la[lb] = v.x; la[lb + 1] = v.y; la[lb + 2] = v.z; la[lb + 3] = v.w;
    }
    __syncthreads();
    const int cg = t & 7, rr = t >> 3;
    const int rb = rr * 4 * 65;
    const int nout = ty ? 2 : 3;
#pragma unroll
    for (int o = 0; o < 3; o++) {
        if (o >= nout) break;
        const int which = ty ? (o == 0 ? 1 : 4) : (o == 0 ? 0 : (o == 1 ? 2 : 3));
        const float* __restrict__ W = Weff + which * 4096;
        float4 a0c[4], a1c[4];
#pragma unroll
        for (int j = 0; j < 4; j++) {
            a0c[j] = make_float4(0.f, 0.f, 0.f, 0.f);
            a1c[j] = make_float4(0.f, 0.f, 0.f, 0.f);
        }
#pragma unroll 8
        for (int k = 0; k < 64; k++) {
            float a0 = la[rb + k];
            float a1 = la[rb + 65 + k];
            float a2 = la[rb + 130 + k];
            float a3 = la[rb + 195 + k];
            const float4* w4 = reinterpret_cast<const float4*>(W + k * 64 + cg * 8);
            float4 w0 = w4[0], w1 = w4[1];
            a0c[0].x = fmaf(a0, w0.x, a0c[0].x); a0c[0].y = fmaf(a0, w0.y, a0c[0].y);
            a0c[0].z = fmaf(a0, w0.z, a0c[0].z); a0c[0].w = fmaf(a0, w0.w, a0c[0].w);
            a1c[0].x = fmaf(a0, w1.x, a1c[0].x); a1c[0].y = fmaf(a0, w1.y, a1c[0].y);
            a1c[0].z = fmaf(a0, w1.z, a1c[0].z); a1c[0].w = fmaf(a0, w1.w, a1c[0].w);
            a0c[1].x = fmaf(a1, w0.x, a0c[1].x); a0c[1].y = fmaf(a1, w0.y, a0c[1].y);
            a0c[1].z = fmaf(a1, w0.z, a0c[1].z); a0c[1].w = fmaf(a1, w0.w, a0c[1].w);
            a1c[1].x = fmaf(a1, w1.x, a1c[1].x); a1c[1].y = fmaf(a1, w1.y, a1c[1].y);
            a1c[1].z = fmaf(a1, w1.z, a1c[1].z); a1c[1].w = fmaf(a1, w1.w, a1c[1].w);
            a0c[2].x = fmaf(a2, w0.x, a0c[2].x); a0c[2].y = fmaf(a2, w0.y, a0c[2].y);
            a0c[2].z = fmaf(a2, w0.z, a0c[2].z); a0c[2].w = fmaf(a2, w0.w, a0c[2].w);
            a1c[2].x = fmaf(a2, w1.x, a1c[2].x); a1c[2].y = fmaf(a2, w1.y, a1c[2].y);
            a1c[2].z = fmaf(a2, w1.z, a1c[2].z); a1c[2].w = fmaf(a2, w1.w, a1c[2].w);
            a0c[3].x = fmaf(a3, w0.x, a0c[3].x); a0c[3].y = fmaf(a3, w0.y, a0c[3].y);
            a0c[3].z = fmaf(a3, w0.z, a0c[3].z); a0c[3].w = fmaf(a3, w0.w, a0c[3].w);
            a1c[3].x = fmaf(a3, w1.x, a1c[3].x); a1c[3].y = fmaf(a3, w1.y, a1c[3].y);
            a1c[3].z = fmaf(a3, w1.z, a1c[3].z); a1c[3].w = fmaf(a3, w1.w, a1c[3].w);
        }
        uint* __restrict__ out = Tb + (size_t)which * (NH / 2);
#pragma unroll
        for (int j = 0; j < 4; j++) {
            int grow = base + rr * 4 + j;
            if (grow < NN) {
                uint4 pk;
                pk.x = pack2(a0c[j].x, a0c[j].y);
                pk.y = pack2(a0c[j].z, a0c[j].w);
                pk.z = pack2(a1c[j].x, a1c[j].y);
                pk.w = pack2(a1c[j].z, a1c[j].w);
                *reinterpret_cast<uint4*>(out + (size_t)grow * 32 + cg * 4) = pk;
            }
        }
    }
}

// ---------------- merged aggregation (y1 + y0 in one launch) ----------------
// grid 25000: slots 0..NN-1 -> y1 rows (message 0); slots NN.. -> y0 rows (1&2).
__global__ __launch_bounds__(256) void agg_all_kernel(
    const uint* __restrict__ T0, const uint* __restrict__ T1,
    const uint* __restrict__ T2, const uint* __restrict__ D0,
    const uint* __restrict__ D1, const int* __restrict__ rowoffs,
    const int* __restrict__ csr, const float* __restrict__ by1,
    const float* __restrict__ by0, float* __restrict__ y1,
    float* __restrict__ y0) {
    const int slot = blockIdx.x * 8 + (threadIdx.x >> 5);
    const int lane = threadIdx.x & 31;
    if (slot < NN) {
        const int row = slot;
        int o0 = rowoffs[row], o1 = rowoffs[row + 1];
        float s0 = 0.f, s1 = 0.f;
        gather4(T0, csr, o0, o1, lane, s0, s1);
        int d = o1 - o0;
        float inv = 1.f / (float)(d > 1 ? d : 1);
        uint dd = D1[(size_t)row * 32 + lane];
        float* yr = y1 + (size_t)row * 64 + lane * 2;
        yr[0] = bf2f(dd & 0xffffu) + s0 * inv + by1[lane * 2];
        yr[1] = bf2f(dd >> 16) + s1 * inv + by1[lane * 2 + 1];
    } else {
        const int row = slot - NN;
        if (row >= NN) return;
        int a0 = rowoffs[NR + row], a1 = rowoffs[NR + row + 1];
        int b0 = rowoffs[2 * NR + row], b1 = rowoffs[2 * NR + row + 1];
        float s10 = 0.f, s11 = 0.f, s20 = 0.f, s21 = 0.f;
        gather4(T1, csr, a0, a1, lane, s10, s11);
        gather4(T2, csr, b0, b1, lane, s20, s21);
        int d1 = a1 - a0, d2 = b1 - b0;
        float i1 = 1.f / (float)(d1 > 1 ? d1 : 1);
        float i2 = 1.f / (float)(d2 > 1 ? d2 : 1);
        uint dd = D0[(size_t)row * 32 + lane];
        float* yr = y0 + (size_t)row * 64 + lane * 2;
        yr[0] = bf2f(dd & 0xffffu) + 0.5f * (s10 * i1 + s20 * i2) + by0[lane * 2];
        yr[1] = bf2f(dd >> 16) + 0.5f * (s11 * i1 + s21 * i2) + by0[lane * 2 + 1];
    }
}

// ---------------- batch-norm stats ----------------
__global__ __launch_bounds__(256) void bn_stats_kernel(
    const float* __restrict__ y0, const float* __restrict__ y1,
    float* __restrict__ accbase) {
    const float* __restrict__ y = blockIdx.y ? y1 : y0;
    float* __restrict__ acc = accbase + blockIdx.y * 128;
    const int col = threadIdx.x & 63, rg = threadIdx.x >> 6;
    float s = 0.f, q = 0.f;
    for (int r = blockIdx.x * 4 + rg; r < NN; r += 256 * 4) {
        float v = y[(size_t)r * 64 + col];
        s += v;
        q = fmaf(v, v, q);
    }
    __shared__ float ls[4][64], lq[4][64];
    ls[rg][col] = s;
    lq[rg][col] = q;
    __syncthreads();
    if (rg == 0) {
        s = ls[0][col] + ls[1][col] + ls[2][col] + ls[3][col];
        q = lq[0][col] + lq[1][col] + lq[2][col] + lq[3][col];
        atomicAdd(&acc[col], s);
        atomicAdd(&acc[64 + col], q);
    }
}

__global__ void bn_fin_kernel(const float* __restrict__ acc,
                              const float* __restrict__ gamma,
                              const float* __restrict__ beta,
                              float* __restrict__ bnss, int l) {
    int t = threadIdx.x;
    if (t >= 128) return;
    int ty = t >> 6, c = t & 63;
    int idx = l * 2 + ty;
    const float invn = 1.0f / (float)NN;
    float mean = acc[idx * 128 + c] * invn;
    float msq = acc[idx * 128 + 64 + c] * invn;
    float var = msq - mean * mean;
    float rs = 1.0f / sqrtf(var + 1.0f);   // eps = 1.0 per reference
    float scv = rs * gamma[idx * 64 + c];
    bnss[idx * 128 + c] = scv;
    bnss[idx * 128 + 64 + c] = beta[idx * 64 + c] - mean * scv;
}

// ---------------- head: out = leaky(bn(y)) @ Wp + bp ----------------
__global__ __launch_bounds__(256) void head_kernel(
    const float* __restrict__ y0, const float* __restrict__ y1,
    const float* __restrict__ Wp, const float* __restrict__ bp,
    const float* __restrict__ ssb, float* __restrict__ outb) {
    constexpr int KPH = 68;
    __shared__ float lw[512];
    __shared__ float la[64 * KPH];
    const int ty = blockIdx.y;
    const float* __restrict__ A = ty ? y1 : y0;
    const float* __restrict__ ss = ssb + ty * 128;
    float* __restrict__ out = outb + (size_t)ty * (NN * 8);
    const int t = threadIdx.x;
    for (int i = t; i < 512; i += 256) lw[i] = Wp[ty * 512 + i];
    const int col = t & 63, rg = t >> 6;
    const float sc = ss[col], sh = ss[64 + col];
    const int base = blockIdx.x * 64;
    const int swz = (col & 3) << 3;
#pragma unroll
    for (int i = 0; i < 16; i++) {
        int r = rg * 16 + i;
        int grow = base + r;
        float v = 0.f;
        if (grow < NN) {
            v = A[(size_t)grow * 64 + col];
            v = fmaf(v, sc, sh);
            v = (v >= 0.f) ? v : 0.01f * v;
        }
        la[col * KPH + (r ^ swz)] = v;
    }
    __syncthreads();
    const int c = t & 7, rp = t >> 3;
    float o0 = 0.f, o1 = 0.f;
#pragma unroll
    for (int k = 0; k < 64; k++) {
        float w = lw[k * 8 + c];
        int pos = k * KPH + ((rp * 2) ^ ((k & 3) << 3));
        o0 = fmaf(la[pos], w, o0);
        o1 = fmaf(la[pos + 1], w, o1);
    }
    float b = bp[ty * 8 + c];
    int g0 = base + rp * 2;
    if (g0 < NN) out[(size_t)g0 * 8 + c] = o0 + b;
    if (g0 + 1 < NN) out[(size_t)(g0 + 1) * 8 + c] = o1 + b;
}

// ---------------- launch ----------------
extern "C" void kernel_launch(void* const* d_in, const int* in_sizes, int n_in,
                              void* d_out, int out_size, void* d_ws, size_t ws_size,
                              hipStream_t stream) {
    const float* x0 = (const float*)d_in[0];
    const float* x1 = (const float*)d_in[1];
    const int* e0 = (const int*)d_in[2];
    const int* e1 = (const int*)d_in[3];
    const int* e2 = (const int*)d_in[4];
    const float* Wsrc = (const float*)d_in[5];
    const float* bsrc = (const float*)d_in[6];
    const float* Wdst = (const float*)d_in[7];
    const float* bdst = (const float*)d_in[8];
    const float* Wupd = (const float*)d_in[9];
    const float* bupd = (const float*)d_in[10];
    const float* gamma = (const float*)d_in[11];
    const float* beta = (const float*)d_in[12];
    const float* Wp = (const float*)d_in[13];
    const float* bp = (const float*)d_in[14];
    float* outp = (float*)d_out;

    // workspace layout (~145 MB)
    uint* Tb = (uint*)d_ws;               // 5 bf16 buffers [N,64]: 5*NH/2 uints
    float* y0 = (float*)(Tb + 5 * (NH / 2));
    float* y1 = y0 + NH;
    float* Weff = y1 + NH;                // 2*5*4096 = 40960
    float* by1p = Weff + 40960;           // 128
    float* by0p = by1p + 128;             // 128
    float* bnacc = by0p + 128;            // 512
    float* bnss = bnacc + 512;            // 512
    int* cnt = (int*)(bnss + 512);        // 3*PBLK*NB = 150048
    int* tot = cnt + 3 * PBLK * NB;       // NBT
    int* boffs = tot + NBT;               // NBT + 1
    int* blkoff = boffs + NBT + 1;        // 3*PBLK*NB
    int* rowoffs = blkoff + 3 * PBLK * NB;// 3*NR + 1
    int* csr = rowoffs + 3 * NR + 1;      // 3E sorted src ids
    uint* be = (uint*)(csr + 3 * NE);     // 3E packed bucketed edges
    (void)in_sizes; (void)n_in; (void)out_size; (void)ws_size;

    const uint* T0 = Tb;
    const uint* T1 = Tb + 1 * (NH / 2);
    const uint* T2 = Tb + 2 * (NH / 2);
    const uint* D0 = Tb + 3 * (NH / 2);
    const uint* D1 = Tb + 4 * (NH / 2);

    // ---- deterministic partition (no global atomics) + sort + weight prep ----
    zero_kernel<<<2, 256, 0, stream>>>(bnacc);
    prep_kernel<<<161, 256, 0, stream>>>(Wsrc, bsrc, Wdst, bdst, Wupd, bupd,
                                         Weff, by1p, by0p);
    bhist2_kernel<<<dim3(PBLK, 3), 256, 0, stream>>>(e0, e1, e2, cnt);
    colsum_kernel<<<19, 256, 0, stream>>>(cnt, tot);
    bscan_kernel<<<1, 256, 0, stream>>>(tot, boffs);
    colpre_kernel<<<19, 256, 0, stream>>>(cnt, boffs, blkoff);
    bscat2_kernel<<<dim3(PBLK, 3), 256, 0, stream>>>(e0, e1, e2, blkoff, be);
    bsort_kernel<<<dim3(NB, 3), 256, 0, stream>>>(boffs, be, csr, rowoffs);

    // ---- layer 0 ----
    gemmA_kernel<false><<<dim3(782, 2), 256, 0, stream>>>(x0, x1, Weff, nullptr,
                                                          nullptr, Tb);
    agg_all_kernel<<<25000, 256, 0, stream>>>(T0, T1, T2, D0, D1, rowoffs, csr,
                                              by1p, by0p, y1, y0);
    bn_stats_kernel<<<dim3(256, 2), 256, 0, stream>>>(y0, y1, bnacc);
    bn_fin_kernel<<<1, 128, 0, stream>>>(bnacc, gamma, beta, bnss, 0);

    // ---- layer 1 (BN+leaky fused into GEMM loads) ----
    gemmA_kernel<true><<<dim3(782, 2), 256, 0, stream>>>(y0, y1, Weff + 20480,
                                                         bnss, bnss + 128, Tb);
    agg_all_kernel<<<25000, 256, 0, stream>>>(T0, T1, T2, D0, D1, rowoffs, csr,
                                              by1p + 64, by0p + 64, y1, y0);
    bn_stats_kernel<<<dim3(256, 2), 256, 0, stream>>>(y0, y1, bnacc + 256);
    bn_fin_kernel<<<1, 128, 0, stream>>>(bnacc, gamma, beta, bnss, 1);

    // ---- heads (BN+leaky fused) ----
    head_kernel<<<dim3(1563, 2), 256, 0, stream>>>(y0, y1, Wp, bp, bnss + 256, outp);
}